// Round 3
// baseline (732.484 us; speedup 1.0000x reference)
//
#include <hip/hip_runtime.h>
#include <cstdint>
#include <cstddef>

#define DN 128
#define NND 50000
#define NED 512000
#define NSCAN 49   // ceil(NND/1024)

typedef __attribute__((ext_vector_type(8))) short bf8;
typedef __attribute__((ext_vector_type(4))) float f4;
typedef unsigned short us;

__device__ __forceinline__ us f2bf(float f){
  union { float f; unsigned int u; } c; c.f = f;
  unsigned int r = c.u + 0x7fffu + ((c.u >> 16) & 1u);
  return (us)(r >> 16);
}
__device__ __forceinline__ float bf2f(us u){
  union { unsigned int u; float f; } c; c.u = ((unsigned int)u) << 16;
  return c.f;
}
// mish(x) = x*tanh(softplus(x)) = x*(u^2-1)/(u^2+1), u = 1+exp(x)
__device__ __forceinline__ float mishf(float x){
  float e = __expf(x);
  float u = 1.f + e;
  float u2 = u * u;
  float t = (u2 - 1.f) / (u2 + 1.f);
  return x * ((x > 20.f) ? 1.f : t);
}

#define MFMA16(a, b, c) __builtin_amdgcn_mfma_f32_16x16x32_bf16((a), (b), (c), 0, 0, 0)

// LDS fragment read: row-major [rows][K] bf16 with (row&7)<<4 byte XOR swizzle.
__device__ __forceinline__ bf8 lds_frag(const us* base, int row, int rowStrideB, int kElem){
  int byte = row * rowStrideB + kElem * 2;
  byte ^= (row & 7) << 4;
  return *(const bf8*)((const char*)base + byte);
}
// Global weight fragment: W^T stored [Nout][K] bf16, plain row-major.
__device__ __forceinline__ bf8 gfrag(const us* W, int n, int K, int kElem){
  return *(const bf8*)(W + (size_t)n * K + kElem);
}

template<int OUT_BF16>
__device__ __forceinline__ void store_tile(void* outp, int nrows, int r0,
                                           int wr, int wc, int g, int s, int ostride,
                                           const f4 (&A)[2][4]){
#pragma unroll
  for (int rt = 0; rt < 2; ++rt)
#pragma unroll
    for (int ct = 0; ct < 4; ++ct)
#pragma unroll
      for (int reg = 0; reg < 4; ++reg){
        int row = r0 + wr*32 + rt*16 + g*4 + reg;
        if (row < nrows){
          int col = wc*64 + ct*16 + s;
          float v = A[rt][ct][reg];
          if constexpr (OUT_BF16 != 0)
            ((us*)outp)[(size_t)row*ostride + col] = f2bf(v);
          else
            ((float*)outp)[(size_t)row*ostride + col] = v;
        }
      }
}

// GEMM1: acc = bias + A(regs) @ W^T
__device__ __forceinline__ void gemm_reg(const bf8 (&a)[2][4], const us* __restrict__ WT,
                                         const float* __restrict__ bias,
                                         int wc, int g, int s, f4 (&acc)[2][4]){
#pragma unroll
  for (int ct = 0; ct < 4; ++ct){
    float bv = bias ? bias[wc*64 + ct*16 + s] : 0.f;
    f4 t = {bv, bv, bv, bv};
    acc[0][ct] = t; acc[1][ct] = t;
  }
#pragma unroll
  for (int ct = 0; ct < 4; ++ct){
    int n = wc*64 + ct*16 + s;
#pragma unroll
    for (int kk = 0; kk < 4; ++kk){
      bf8 b = gfrag(WT, n, DN, kk*32 + g*8);
      acc[0][ct] = MFMA16(a[0][kk], b, acc[0][ct]);
      acc[1][ct] = MFMA16(a[1][kk], b, acc[1][ct]);
    }
  }
}

// LN across the 128-wide row (two waves share a row) + mish. Uses buf parity to
// avoid WAR races on the stats arrays between consecutive chains.
__device__ __forceinline__ void ln_mish(f4 (&acc)[2][4],
                                        const float* __restrict__ gam,
                                        const float* __restrict__ bet,
                                        int wr, int wc, int g, int s,
                                        float (*rowsum)[64][2], float (*rowsq)[64][2],
                                        int buf){
  float gv[4], bev[4];
#pragma unroll
  for (int ct = 0; ct < 4; ++ct){ int n = wc*64 + ct*16 + s; gv[ct] = gam[n]; bev[ct] = bet[n]; }
#pragma unroll
  for (int rt = 0; rt < 2; ++rt)
#pragma unroll
    for (int reg = 0; reg < 4; ++reg){
      float sm = acc[rt][0][reg] + acc[rt][1][reg] + acc[rt][2][reg] + acc[rt][3][reg];
      float sq = acc[rt][0][reg]*acc[rt][0][reg] + acc[rt][1][reg]*acc[rt][1][reg]
               + acc[rt][2][reg]*acc[rt][2][reg] + acc[rt][3][reg]*acc[rt][3][reg];
#pragma unroll
      for (int m = 1; m < 16; m <<= 1){ sm += __shfl_xor(sm, m, 64); sq += __shfl_xor(sq, m, 64); }
      if (s == 0){
        int row = wr*32 + rt*16 + g*4 + reg;
        rowsum[buf][row][wc] = sm; rowsq[buf][row][wc] = sq;
      }
    }
  __syncthreads();
#pragma unroll
  for (int rt = 0; rt < 2; ++rt)
#pragma unroll
    for (int reg = 0; reg < 4; ++reg){
      int row = wr*32 + rt*16 + g*4 + reg;
      float sm = rowsum[buf][row][0] + rowsum[buf][row][1];
      float sq = rowsq[buf][row][0] + rowsq[buf][row][1];
      float mu = sm * (1.f/128.f);
      float var = sq * (1.f/128.f) - mu*mu;
      float rs = rsqrtf(var + 1e-5f);
#pragma unroll
      for (int ct = 0; ct < 4; ++ct)
        acc[rt][ct][reg] = mishf((acc[rt][ct][reg] - mu) * rs * gv[ct] + bev[ct]);
    }
}

__device__ __forceinline__ void write_T(us* Tsh, int wr, int wc, int g, int s,
                                        const f4 (&A)[2][4]){
#pragma unroll
  for (int rt = 0; rt < 2; ++rt)
#pragma unroll
    for (int ct = 0; ct < 4; ++ct)
#pragma unroll
      for (int reg = 0; reg < 4; ++reg){
        int row = wr*32 + rt*16 + g*4 + reg;
        int col = wc*64 + ct*16 + s;
        int byte = row*256 + col*2; byte ^= (row & 7) << 4;
        *(us*)((char*)Tsh + byte) = f2bf(A[rt][ct][reg]);
      }
}

__device__ __forceinline__ void load_a2(const us* Tsh, int wr, int g, int s, bf8 (&a2)[2][4]){
#pragma unroll
  for (int rt = 0; rt < 2; ++rt)
#pragma unroll
    for (int kk = 0; kk < 4; ++kk)
      a2[rt][kk] = lds_frag(Tsh, wr*32 + rt*16 + s, 256, kk*32 + g*8);
}

// ---------- Fused node chains: q, k, m(2 GEMM), b(2 GEMM), c(2 GEMM, no LN) ----------
__global__ __launch_bounds__(256, 3)
void node_fused(const float* __restrict__ X,
                const us* __restrict__ WqT,  const float* __restrict__ bq,
                const float* __restrict__ gq, const float* __restrict__ beq,
                const us* __restrict__ WkT,  const float* __restrict__ bk,
                const float* __restrict__ gk, const float* __restrict__ bek,
                const us* __restrict__ Wm1T, const float* __restrict__ bm1,
                const float* __restrict__ gm, const float* __restrict__ bem,
                const us* __restrict__ Wm2T, const float* __restrict__ bm2,
                const us* __restrict__ Wb1T, const float* __restrict__ bb1,
                const float* __restrict__ gb, const float* __restrict__ beb,
                const us* __restrict__ Wb2T, const float* __restrict__ bb2,
                const us* __restrict__ Wc1T, const float* __restrict__ bc1,
                const us* __restrict__ Wc2T,
                us* __restrict__ qt, us* __restrict__ kmb, float* __restrict__ xout)
{
  __shared__ us Ash[64 * DN];
  __shared__ float rowsum[2][64][2];
  __shared__ float rowsq[2][64][2];

  const int tid = threadIdx.x;
  const int r0 = blockIdx.x * 64;

  { // stage X rows -> bf16 swizzled LDS (once, shared by 8 GEMMs)
    int r = tid >> 2, c4 = tid & 3;
    int grow = r0 + r; if (grow >= NND) grow = NND - 1;
    const f4* sp = (const f4*)(X + (size_t)grow * DN + c4 * 32);
#pragma unroll
    for (int j = 0; j < 4; ++j){
      f4 v0 = sp[2*j], v1 = sp[2*j+1];
      bf8 o;
#pragma unroll
      for (int q = 0; q < 4; ++q){ o[q] = (short)f2bf(v0[q]); o[4+q] = (short)f2bf(v1[q]); }
      int byte = r*256 + c4*64 + j*16; byte ^= (r & 7) << 4;
      *(bf8*)((char*)Ash + byte) = o;
    }
  }
  __syncthreads();

  const int lane = tid & 63, w = tid >> 6;
  const int wr = w >> 1, wc = w & 1;
  const int g = lane >> 4, s = lane & 15;

  bf8 a[2][4];
#pragma unroll
  for (int rt = 0; rt < 2; ++rt)
#pragma unroll
    for (int kk = 0; kk < 4; ++kk)
      a[rt][kk] = lds_frag(Ash, wr*32 + rt*16 + s, 256, kk*32 + g*8);
  __syncthreads();   // all A-frag reads done -> Ash reusable as T

  f4 acc[2][4], acc2[2][4];
  bf8 a2[2][4];

  // ---- q ----
  gemm_reg(a, WqT, bq, wc, g, s, acc);
  ln_mish(acc, gq, beq, wr, wc, g, s, rowsum, rowsq, 0);
  store_tile<1>((void*)qt, NND, r0, wr, wc, g, s, DN, acc);

  // ---- k ----
  gemm_reg(a, WkT, bk, wc, g, s, acc);
  ln_mish(acc, gk, bek, wr, wc, g, s, rowsum, rowsq, 1);
  store_tile<1>((void*)kmb, NND, r0, wr, wc, g, s, 384, acc);

  // ---- m (2 GEMM) ----
  gemm_reg(a, Wm1T, bm1, wc, g, s, acc);
  ln_mish(acc, gm, bem, wr, wc, g, s, rowsum, rowsq, 0);   // its sync fences k's LN reads + prior Ash reads
  write_T(Ash, wr, wc, g, s, acc);
  __syncthreads();
  load_a2(Ash, wr, g, s, a2);
#pragma unroll
  for (int ct = 0; ct < 4; ++ct){
    float bv = bm2[wc*64 + ct*16 + s]; f4 t = {bv,bv,bv,bv}; acc2[0][ct] = t; acc2[1][ct] = t;
  }
#pragma unroll
  for (int ct = 0; ct < 4; ++ct){
    int n = wc*64 + ct*16 + s;
#pragma unroll
    for (int kk = 0; kk < 4; ++kk){
      bf8 b = gfrag(Wm2T, n, DN, kk*32 + g*8);
      acc2[0][ct] = MFMA16(a2[0][kk], b, acc2[0][ct]);
      acc2[1][ct] = MFMA16(a2[1][kk], b, acc2[1][ct]);
    }
  }
  store_tile<1>((void*)(kmb + 128), NND, r0, wr, wc, g, s, 384, acc2);

  // ---- b (2 GEMM) ----
  gemm_reg(a, Wb1T, bb1, wc, g, s, acc);
  ln_mish(acc, gb, beb, wr, wc, g, s, rowsum, rowsq, 1);   // sync fences m's a2 reads
  write_T(Ash, wr, wc, g, s, acc);
  __syncthreads();
  load_a2(Ash, wr, g, s, a2);
#pragma unroll
  for (int ct = 0; ct < 4; ++ct){
    float bv = bb2[wc*64 + ct*16 + s]; f4 t = {bv,bv,bv,bv}; acc2[0][ct] = t; acc2[1][ct] = t;
  }
#pragma unroll
  for (int ct = 0; ct < 4; ++ct){
    int n = wc*64 + ct*16 + s;
#pragma unroll
    for (int kk = 0; kk < 4; ++kk){
      bf8 b = gfrag(Wb2T, n, DN, kk*32 + g*8);
      acc2[0][ct] = MFMA16(a2[0][kk], b, acc2[0][ct]);
      acc2[1][ct] = MFMA16(a2[1][kk], b, acc2[1][ct]);
    }
  }
  store_tile<1>((void*)(kmb + 256), NND, r0, wr, wc, g, s, 384, acc2);

  // ---- c (2 GEMM, no LN) ----
  gemm_reg(a, Wc1T, bc1, wc, g, s, acc);
#pragma unroll
  for (int rt = 0; rt < 2; ++rt)
#pragma unroll
    for (int ct = 0; ct < 4; ++ct)
#pragma unroll
      for (int reg = 0; reg < 4; ++reg)
        acc[rt][ct][reg] = mishf(acc[rt][ct][reg]);
  __syncthreads();                    // fence b's a2 reads before overwriting Ash
  write_T(Ash, wr, wc, g, s, acc);
  __syncthreads();
  load_a2(Ash, wr, g, s, a2);
#pragma unroll
  for (int ct = 0; ct < 4; ++ct){ f4 t = {0,0,0,0}; acc2[0][ct] = t; acc2[1][ct] = t; }
#pragma unroll
  for (int ct = 0; ct < 4; ++ct){
    int n = wc*64 + ct*16 + s;
#pragma unroll
    for (int kk = 0; kk < 4; ++kk){
      bf8 b = gfrag(Wc2T, n, DN, kk*32 + g*8);
      acc2[0][ct] = MFMA16(a2[0][kk], b, acc2[0][ct]);
      acc2[1][ct] = MFMA16(a2[1][kk], b, acc2[1][ct]);
    }
  }
  store_tile<0>((void*)xout, NND, r0, wr, wc, g, s, DN, acc2);
}

// ---------- CSR build ----------
__global__ void csr_count(const int* __restrict__ dst, int* __restrict__ deg){
  int e = blockIdx.x * 256 + threadIdx.x;
  if (e < NED) atomicAdd(&deg[dst[e]], 1);
}

__global__ __launch_bounds__(1024) void csr_blocksum(const int* __restrict__ deg,
                                                     int* __restrict__ bsum){
  __shared__ int sb[1024];
  int t = threadIdx.x, idx = blockIdx.x * 1024 + t;
  sb[t] = (idx < NND) ? deg[idx] : 0;
  __syncthreads();
  for (int off = 512; off > 0; off >>= 1){
    if (t < off) sb[t] += sb[t + off];
    __syncthreads();
  }
  if (t == 0) bsum[blockIdx.x] = sb[0];
}

__global__ void csr_scanroot(const int* __restrict__ bsum, int* __restrict__ boff,
                             int* __restrict__ ptr){
  if (threadIdx.x == 0){
    int run = 0;
    for (int b = 0; b < NSCAN; ++b){ boff[b] = run; run += bsum[b]; }
    ptr[NND] = run;
  }
}

__global__ __launch_bounds__(1024) void csr_scatter(const int* __restrict__ deg,
                                                    const int* __restrict__ boff,
                                                    int* __restrict__ ptr,
                                                    int* __restrict__ fillctr){
  __shared__ int ss[1024];
  int t = threadIdx.x, idx = blockIdx.x * 1024 + t;
  int v = (idx < NND) ? deg[idx] : 0;
  ss[t] = v;
  __syncthreads();
  for (int off = 1; off < 1024; off <<= 1){
    int x = (t >= off) ? ss[t - off] : 0;
    __syncthreads();
    ss[t] += x;
    __syncthreads();
  }
  if (idx < NND){
    int p = boff[blockIdx.x] + ss[t] - v;
    ptr[idx] = p; fillctr[idx] = p;
  }
}

__global__ void csr_fill(const int* __restrict__ src, const int* __restrict__ dst,
                         int* __restrict__ fillctr,
                         int* __restrict__ ssorted, int* __restrict__ dsorted){
  int e = blockIdx.x * 256 + threadIdx.x;
  if (e < NED){
    int d = dst[e];
    int p = atomicAdd(&fillctr[d], 1);
    ssorted[p] = src[e];
    dsorted[p] = d;
  }
}

// ---------- Edge pass (sorted-by-dst order): rel -> GEMM+LN+mish -> GEMM -> exp -> pbuf + colsum ----------
__global__ __launch_bounds__(256, 4)
void edge_kernel(const us* __restrict__ qtab,
                 const us* __restrict__ kmb,   // [N][384]: k|m|b
                 const us* __restrict__ W1T,
                 const us* __restrict__ W2T,
                 const float* __restrict__ bw1,
                 const float* __restrict__ gwp,
                 const float* __restrict__ bewp,
                 const float* __restrict__ bw2,
                 const int* __restrict__ ssorted,
                 const int* __restrict__ dsorted,
                 us* __restrict__ pbuf,        // [E][128] bf16 = exp(w), sorted order
                 float* __restrict__ colsum)
{
  __shared__ us Ash[64 * DN];                 // staged rel -> T -> p (reused)
  __shared__ float rowsum[1][64][2];
  __shared__ float rowsq[1][64][2];
  __shared__ float csh[DN];

  const int tid = threadIdx.x;
  // XCD-chunked swizzle: 8000 blocks -> each XCD gets a contiguous sorted range
  const int nchunk = gridDim.x >> 3;
  const int swz = (blockIdx.x & 7) * nchunk + (blockIdx.x >> 3);
  const int e0 = swz * 64;
  const int lane = tid & 63, w = tid >> 6;
  const int wr = w >> 1, wc = w & 1;
  const int g = lane >> 4, s = lane & 15;

  if (tid < DN) csh[tid] = 0.f;

  // register-pinned weight fragments (per wave)
  bf8 B1[4][4], B2[4][4];
  float b1v[4], gv[4], bev[4], b2v[4];
#pragma unroll
  for (int ct = 0; ct < 4; ++ct){
    int n = wc*64 + ct*16 + s;
#pragma unroll
    for (int kk = 0; kk < 4; ++kk){
      B1[ct][kk] = gfrag(W1T, n, DN, kk*32 + g*8);
      B2[ct][kk] = gfrag(W2T, n, DN, kk*32 + g*8);
    }
    b1v[ct] = bw1[n]; gv[ct] = gwp[n]; bev[ct] = bewp[n]; b2v[ct] = bw2[n];
  }

  { // gather + rel construction -> Ash
    int r = tid >> 2, c4 = tid & 3;
    int e = e0 + r;
    int sn = ssorted[e], dn = dsorted[e];
    const bf8* qp = (const bf8*)(qtab + (size_t)sn * DN + c4 * 32);
    const us* kb = kmb + (size_t)dn * 384 + c4 * 32;
    float rel[32]; float ss = 0.f;
#pragma unroll
    for (int j = 0; j < 4; ++j){
      bf8 qv = qp[j];
      bf8 kv = *(const bf8*)(kb + j*8);
#pragma unroll
      for (int q = 0; q < 8; ++q){
        float d = bf2f((us)qv[q]) - bf2f((us)kv[q]);
        rel[j*8+q] = d; ss += d * d;
      }
    }
    ss += __shfl_xor(ss, 1, 64);
    ss += __shfl_xor(ss, 2, 64);
    float rinv = rsqrtf(ss + 1e-8f);
#pragma unroll
    for (int j = 0; j < 4; ++j){
      bf8 mv = *(const bf8*)(kb + 128 + j*8);
      bf8 bv = *(const bf8*)(kb + 256 + j*8);
      bf8 o;
#pragma unroll
      for (int q = 0; q < 8; ++q){
        float v = rel[j*8+q] * rinv * bf2f((us)mv[q]) + bf2f((us)bv[q]);
        o[q] = (short)f2bf(v);
      }
      int byte = r*256 + c4*64 + j*16; byte ^= (r & 7) << 4;
      *(bf8*)((char*)Ash + byte) = o;
    }
  }
  __syncthreads();   // (1)

  // GEMM1 from Ash
  f4 acc[2][4];
#pragma unroll
  for (int ct = 0; ct < 4; ++ct){ f4 t = {b1v[ct], b1v[ct], b1v[ct], b1v[ct]}; acc[0][ct] = t; acc[1][ct] = t; }
  bf8 a[2][4];
#pragma unroll
  for (int rt = 0; rt < 2; ++rt)
#pragma unroll
    for (int kk = 0; kk < 4; ++kk)
      a[rt][kk] = lds_frag(Ash, wr*32 + rt*16 + s, 256, kk*32 + g*8);
#pragma unroll
  for (int ct = 0; ct < 4; ++ct)
#pragma unroll
    for (int kk = 0; kk < 4; ++kk){
      acc[0][ct] = MFMA16(a[0][kk], B1[ct][kk], acc[0][ct]);
      acc[1][ct] = MFMA16(a[1][kk], B1[ct][kk], acc[1][ct]);
    }

  // LN + mish (internal sync (2) fences all Ash A-frag reads)
#pragma unroll
  for (int rt = 0; rt < 2; ++rt)
#pragma unroll
    for (int reg = 0; reg < 4; ++reg){
      float sm = acc[rt][0][reg] + acc[rt][1][reg] + acc[rt][2][reg] + acc[rt][3][reg];
      float sq = acc[rt][0][reg]*acc[rt][0][reg] + acc[rt][1][reg]*acc[rt][1][reg]
               + acc[rt][2][reg]*acc[rt][2][reg] + acc[rt][3][reg]*acc[rt][3][reg];
#pragma unroll
      for (int m = 1; m < 16; m <<= 1){ sm += __shfl_xor(sm, m, 64); sq += __shfl_xor(sq, m, 64); }
      if (s == 0){
        int row = wr*32 + rt*16 + g*4 + reg;
        rowsum[0][row][wc] = sm; rowsq[0][row][wc] = sq;
      }
    }
  __syncthreads();   // (2)
#pragma unroll
  for (int rt = 0; rt < 2; ++rt)
#pragma unroll
    for (int reg = 0; reg < 4; ++reg){
      int row = wr*32 + rt*16 + g*4 + reg;
      float sm = rowsum[0][row][0] + rowsum[0][row][1];
      float sq = rowsq[0][row][0] + rowsq[0][row][1];
      float mu = sm * (1.f/128.f);
      float var = sq * (1.f/128.f) - mu*mu;
      float rs = rsqrtf(var + 1e-5f);
#pragma unroll
      for (int ct = 0; ct < 4; ++ct)
        acc[rt][ct][reg] = mishf((acc[rt][ct][reg] - mu) * rs * gv[ct] + bev[ct]);
    }

  // T -> Ash (reuse)
  write_T(Ash, wr, wc, g, s, acc);
  __syncthreads();   // (3)

  // GEMM2 -> p = exp(w)
  f4 p[2][4];
#pragma unroll
  for (int ct = 0; ct < 4; ++ct){ f4 t = {b2v[ct], b2v[ct], b2v[ct], b2v[ct]}; p[0][ct] = t; p[1][ct] = t; }
  bf8 a2[2][4];
  load_a2(Ash, wr, g, s, a2);
#pragma unroll
  for (int ct = 0; ct < 4; ++ct)
#pragma unroll
    for (int kk = 0; kk < 4; ++kk){
      p[0][ct] = MFMA16(a2[0][kk], B2[ct][kk], p[0][ct]);
      p[1][ct] = MFMA16(a2[1][kk], B2[ct][kk], p[1][ct]);
    }
#pragma unroll
  for (int rt = 0; rt < 2; ++rt)
#pragma unroll
    for (int ct = 0; ct < 4; ++ct)
#pragma unroll
      for (int reg = 0; reg < 4; ++reg)
        p[rt][ct][reg] = __expf(p[rt][ct][reg]);

  // per-column partial sums
#pragma unroll
  for (int ct = 0; ct < 4; ++ct){
    float cp = 0.f;
#pragma unroll
    for (int rt = 0; rt < 2; ++rt)
#pragma unroll
      for (int reg = 0; reg < 4; ++reg) cp += p[rt][ct][reg];
    cp += __shfl_xor(cp, 16, 64);
    cp += __shfl_xor(cp, 32, 64);
    if (g == 0) atomicAdd(&csh[wc*64 + ct*16 + s], cp);
  }
  __syncthreads();   // (4) a2 reads + csh adds done

  // p -> Ash (bf16, swizzled) for coalesced global store
  write_T(Ash, wr, wc, g, s, p);
  __syncthreads();   // (5)

  { // coalesced 16B stores: 64 rows x 256B, sorted position
    int r = tid >> 2, c4 = tid & 3;
    us* dp = pbuf + (size_t)(e0 + r) * DN + c4 * 32;
#pragma unroll
    for (int j = 0; j < 4; ++j){
      int byte = r*256 + c4*64 + j*16; byte ^= (r & 7) << 4;
      bf8 v = *(const bf8*)((const char*)Ash + byte);
      *(bf8*)(dp + j*8) = v;
    }
  }
  if (tid < DN) atomicAdd(&colsum[tid], csh[tid]);
}

// ---------- final: h_neigh gather (sequential CSR range) + concat GEMMs ----------
__global__ __launch_bounds__(256, 3)
void final_h(const float* __restrict__ nodef,
             const us* __restrict__ pbuf,
             const int* __restrict__ ptr,
             const float* __restrict__ colsum,
             const us* __restrict__ Wn1T,
             const float* __restrict__ bn1,
             const us* __restrict__ Wn2T,
             const float* __restrict__ bn2,
             float* __restrict__ outh)
{
  __shared__ us Ash[64 * 256];   // [64 rows][256 cols] bf16, stride 512B

  const int tid = threadIdx.x;
  const int r0 = blockIdx.x * 64;
  const int lane = tid & 63, w = tid >> 6;

  { // stage node_feat rows -> cols 0..127
    int r = tid >> 2, c4 = tid & 3;
    int grow = r0 + r; if (grow >= NND) grow = NND - 1;
    const f4* np = (const f4*)(nodef + (size_t)grow * DN + c4 * 32);
#pragma unroll
    for (int j = 0; j < 4; ++j){
      f4 v0 = np[2*j], v1 = np[2*j+1];
      bf8 o;
#pragma unroll
      for (int q = 0; q < 4; ++q){ o[q] = (short)f2bf(v0[q]); o[4+q] = (short)f2bf(v1[q]); }
      int byte = r*512 + c4*64 + j*16; byte ^= (r & 7) << 4;
      *(bf8*)((char*)Ash + byte) = o;
    }
  }

  { // gather h_neigh (sequential pbuf rows per node) -> cols 128..255
    float c0 = colsum[lane*2], c1 = colsum[lane*2 + 1];
    for (int i = 0; i < 16; ++i){
      int lr = w*16 + i;
      int n = r0 + lr;
      float a0 = 0.f, a1 = 0.f;
      if (n < NND){
        int beg = ptr[n], end = ptr[n+1];
        for (int e = beg; e < end; ++e){
          unsigned int v = *(const unsigned int*)(pbuf + (size_t)e * DN + lane * 2);
          a0 += bf2f((us)(v & 0xffffu));
          a1 += bf2f((us)(v >> 16));
        }
      }
      unsigned int o = ((unsigned int)f2bf(a1 / c1) << 16) | (unsigned int)f2bf(a0 / c0);
      int byte = lr*512 + 256 + lane*4; byte ^= (lr & 7) << 4;
      *(unsigned int*)((char*)Ash + byte) = o;
    }
  }
  __syncthreads();

  const int wr = w >> 1, wc = w & 1;
  const int g = lane >> 4, s = lane & 15;

  float b1v[4], b2v[4];
#pragma unroll
  for (int ct = 0; ct < 4; ++ct){ int n = wc*64 + ct*16 + s; b1v[ct] = bn1[n]; b2v[ct] = bn2[n]; }

  f4 acc[2][4];
#pragma unroll
  for (int ct = 0; ct < 4; ++ct){ f4 t = {b1v[ct], b1v[ct], b1v[ct], b1v[ct]}; acc[0][ct] = t; acc[1][ct] = t; }

  bf8 a[2][8];
#pragma unroll
  for (int rt = 0; rt < 2; ++rt)
#pragma unroll
    for (int kk = 0; kk < 8; ++kk)
      a[rt][kk] = lds_frag(Ash, wr*32 + rt*16 + s, 512, kk*32 + g*8);
  __syncthreads();   // frag reads done -> Ash reusable as T

#pragma unroll
  for (int ct = 0; ct < 4; ++ct){
    int n = wc*64 + ct*16 + s;
#pragma unroll
    for (int kk = 0; kk < 8; ++kk){
      bf8 b = gfrag(Wn1T, n, 256, kk*32 + g*8);
      acc[0][ct] = MFMA16(a[0][kk], b, acc[0][ct]);
      acc[1][ct] = MFMA16(a[1][kk], b, acc[1][ct]);
    }
  }

#pragma unroll
  for (int rt = 0; rt < 2; ++rt)
#pragma unroll
    for (int ct = 0; ct < 4; ++ct)
#pragma unroll
      for (int reg = 0; reg < 4; ++reg)
        acc[rt][ct][reg] = mishf(acc[rt][ct][reg]);
  write_T((us*)Ash, wr, wc, g, s, acc);
  __syncthreads();

  f4 acc2[2][4];
#pragma unroll
  for (int ct = 0; ct < 4; ++ct){ f4 t = {b2v[ct], b2v[ct], b2v[ct], b2v[ct]}; acc2[0][ct] = t; acc2[1][ct] = t; }
  bf8 a2[2][4];
  load_a2((const us*)Ash, wr, g, s, a2);
#pragma unroll
  for (int ct = 0; ct < 4; ++ct){
    int n = wc*64 + ct*16 + s;
#pragma unroll
    for (int kk = 0; kk < 4; ++kk){
      bf8 b = gfrag(Wn2T, n, DN, kk*32 + g*8);
      acc2[0][ct] = MFMA16(a2[0][kk], b, acc2[0][ct]);
      acc2[1][ct] = MFMA16(a2[1][kk], b, acc2[1][ct]);
    }
  }
  store_tile<0>((void*)outh, NND, r0, wr, wc, g, s, DN, acc2);
}

struct WPrepArgs {
  const float* w[12];
  us* wt[12];
  int K[12];
};

// W^T bf16: wt[n*K + k] = bf16(W[k*128 + n])
__global__ void prep_weights(WPrepArgs a){
  int widx = blockIdx.y;
  int K = a.K[widx];
  int idx = blockIdx.x * 256 + threadIdx.x;
  if (idx >= DN * K) return;
  int kshift = (K == 256) ? 8 : 7;
  int n = idx >> kshift;
  int k = idx & (K - 1);
  a.wt[widx][idx] = f2bf(a.w[widx][(size_t)k * DN + n]);
}

extern "C" void kernel_launch(void* const* d_in, const int* in_sizes, int n_in,
                              void* d_out, int out_size, void* d_ws, size_t ws_size,
                              hipStream_t stream) {
  const float* node_feat = (const float*)d_in[0];
  const float* coordf    = (const float*)d_in[1];
  const float* Wq  = (const float*)d_in[2];
  const float* bq  = (const float*)d_in[3];
  const float* gq  = (const float*)d_in[4];
  const float* beq = (const float*)d_in[5];
  const float* Wk  = (const float*)d_in[6];
  const float* bk  = (const float*)d_in[7];
  const float* gk  = (const float*)d_in[8];
  const float* bek = (const float*)d_in[9];
  const float* Wm1 = (const float*)d_in[10];
  const float* bm1 = (const float*)d_in[11];
  const float* gm  = (const float*)d_in[12];
  const float* bem = (const float*)d_in[13];
  const float* Wm2 = (const float*)d_in[14];
  const float* bm2 = (const float*)d_in[15];
  const float* Wb1 = (const float*)d_in[16];
  const float* bb1 = (const float*)d_in[17];
  const float* gb  = (const float*)d_in[18];
  const float* beb = (const float*)d_in[19];
  const float* Wb2 = (const float*)d_in[20];
  const float* bb2 = (const float*)d_in[21];
  const float* Ww1 = (const float*)d_in[22];
  const float* bw1 = (const float*)d_in[23];
  const float* gw  = (const float*)d_in[24];
  const float* bew = (const float*)d_in[25];
  const float* Ww2 = (const float*)d_in[26];
  const float* bw2 = (const float*)d_in[27];
  const float* Wn1 = (const float*)d_in[28];
  const float* bn1 = (const float*)d_in[29];
  const float* Wn2 = (const float*)d_in[30];
  const float* bn2 = (const float*)d_in[31];
  const float* Wc1 = (const float*)d_in[32];
  const float* bc1 = (const float*)d_in[33];
  const float* Wc2 = (const float*)d_in[34];
  const int* srcI  = (const int*)d_in[35];
  const int* dstI  = (const int*)d_in[36];

  char* ws = (char*)d_ws;
  size_t off = 0;
  auto alloc = [&](size_t bytes) -> char* {
    char* p = ws + off;
    off += (bytes + 255) & ~(size_t)255;
    return p;
  };
  us*    qt      = (us*)alloc((size_t)NND * DN * 2);
  us*    kmb     = (us*)alloc((size_t)NND * 384 * 2);
  us*    pbuf    = (us*)alloc((size_t)NED * DN * 2);
  float* colsum  = (float*)alloc(DN * 4);
  int*   deg     = (int*)alloc((size_t)NND * 4);
  int*   ptr     = (int*)alloc((size_t)(NND + 1) * 4);
  int*   fillctr = (int*)alloc((size_t)NND * 4);
  int*   ssorted = (int*)alloc((size_t)NED * 4);
  int*   dsorted = (int*)alloc((size_t)NED * 4);
  int*   bsum    = (int*)alloc((size_t)NSCAN * 4);
  int*   boff    = (int*)alloc((size_t)NSCAN * 4);
  us*    wtb     = (us*)alloc((size_t)12 * 16384 * 2);

  hipMemsetAsync(colsum, 0, DN * 4, stream);
  hipMemsetAsync(deg, 0, (size_t)NND * 4, stream);

  WPrepArgs pa;
  const float* wsrc[12] = {Wq, Wk, Wm1, Wm2, Wb1, Wb2, Ww1, Ww2, Wc1, Wc2, Wn2, Wn1};
  for (int i = 0; i < 12; ++i){
    pa.w[i] = wsrc[i];
    pa.wt[i] = wtb + (size_t)i * 16384;
    pa.K[i] = (i == 11) ? 256 : 128;
  }
  prep_weights<<<dim3(128, 12), 256, 0, stream>>>(pa);

  // CSR build + edge sort by dst
  csr_count<<<(NED + 255) / 256, 256, 0, stream>>>(dstI, deg);
  csr_blocksum<<<NSCAN, 1024, 0, stream>>>(deg, bsum);
  csr_scanroot<<<1, 64, 0, stream>>>(bsum, boff, ptr);
  csr_scatter<<<NSCAN, 1024, 0, stream>>>(deg, boff, ptr, fillctr);
  csr_fill<<<(NED + 255) / 256, 256, 0, stream>>>(srcI, dstI, fillctr, ssorted, dsorted);

  const int NB = (NND + 63) / 64;  // 782

  node_fused<<<NB, 256, 0, stream>>>(coordf,
      pa.wt[0], bq, gq, beq,
      pa.wt[1], bk, gk, bek,
      pa.wt[2], bm1, gm, bem, pa.wt[3], bm2,
      pa.wt[4], bb1, gb, beb, pa.wt[5], bb2,
      pa.wt[8], bc1, pa.wt[9],
      qt, kmb, (float*)d_out + (size_t)NND * DN);

  edge_kernel<<<NED / 64, 256, 0, stream>>>(qt, kmb, pa.wt[6], pa.wt[7],
                                            bw1, gw, bew, bw2, ssorted, dsorted, pbuf, colsum);

  final_h<<<NB, 256, 0, stream>>>(node_feat, pbuf, ptr, colsum,
                                  pa.wt[11], bn1, pa.wt[10], bn2, (float*)d_out);
}

// Round 4
// 601.300 us; speedup vs baseline: 1.2182x; 1.2182x over previous
//
#include <hip/hip_runtime.h>
#include <cstdint>
#include <cstddef>

#define DN 128
#define NND 50000
#define NED 512000
#define NSCAN 49   // ceil(NND/1024)

typedef __attribute__((ext_vector_type(8))) short bf8;
typedef __attribute__((ext_vector_type(4))) float f4;
typedef unsigned short us;

__device__ __forceinline__ us f2bf(float f){
  union { float f; unsigned int u; } c; c.f = f;
  unsigned int r = c.u + 0x7fffu + ((c.u >> 16) & 1u);
  return (us)(r >> 16);
}
__device__ __forceinline__ float bf2f(us u){
  union { unsigned int u; float f; } c; c.u = ((unsigned int)u) << 16;
  return c.f;
}
// mish(x) = x*tanh(softplus(x)) = x*(u^2-1)/(u^2+1), u = 1+exp(x)
__device__ __forceinline__ float mishf(float x){
  float e = __expf(x);
  float u = 1.f + e;
  float u2 = u * u;
  float t = (u2 - 1.f) / (u2 + 1.f);
  return x * ((x > 20.f) ? 1.f : t);
}

#define MFMA16(a, b, c) __builtin_amdgcn_mfma_f32_16x16x32_bf16((a), (b), (c), 0, 0, 0)

// LDS fragment read: row-major [rows][K] bf16 with (row&7)<<4 byte XOR swizzle.
__device__ __forceinline__ bf8 lds_frag(const us* base, int row, int rowStrideB, int kElem){
  int byte = row * rowStrideB + kElem * 2;
  byte ^= (row & 7) << 4;
  return *(const bf8*)((const char*)base + byte);
}
// Global weight fragment: W^T stored [Nout][K] bf16, plain row-major.
__device__ __forceinline__ bf8 gfrag(const us* W, int n, int K, int kElem){
  return *(const bf8*)(W + (size_t)n * K + kElem);
}

template<int OUT_BF16>
__device__ __forceinline__ void store_tile(void* outp, int nrows, int r0,
                                           int wr, int wc, int g, int s, int ostride,
                                           const f4 (&A)[2][4]){
#pragma unroll
  for (int rt = 0; rt < 2; ++rt)
#pragma unroll
    for (int ct = 0; ct < 4; ++ct)
#pragma unroll
      for (int reg = 0; reg < 4; ++reg){
        int row = r0 + wr*32 + rt*16 + g*4 + reg;
        if (row < nrows){
          int col = wc*64 + ct*16 + s;
          float v = A[rt][ct][reg];
          if constexpr (OUT_BF16 != 0)
            ((us*)outp)[(size_t)row*ostride + col] = f2bf(v);
          else
            ((float*)outp)[(size_t)row*ostride + col] = v;
        }
      }
}

// GEMM1: acc = bias + A(regs) @ W^T
__device__ __forceinline__ void gemm_reg(const bf8 (&a)[2][4], const us* __restrict__ WT,
                                         const float* __restrict__ bias,
                                         int wc, int g, int s, f4 (&acc)[2][4]){
#pragma unroll
  for (int ct = 0; ct < 4; ++ct){
    float bv = bias ? bias[wc*64 + ct*16 + s] : 0.f;
    f4 t = {bv, bv, bv, bv};
    acc[0][ct] = t; acc[1][ct] = t;
  }
#pragma unroll
  for (int ct = 0; ct < 4; ++ct){
    int n = wc*64 + ct*16 + s;
#pragma unroll
    for (int kk = 0; kk < 4; ++kk){
      bf8 b = gfrag(WT, n, DN, kk*32 + g*8);
      acc[0][ct] = MFMA16(a[0][kk], b, acc[0][ct]);
      acc[1][ct] = MFMA16(a[1][kk], b, acc[1][ct]);
    }
  }
}

// LN across the 128-wide row (two waves share a row) + mish. Uses buf parity to
// avoid WAR races on the stats arrays between consecutive chains.
__device__ __forceinline__ void ln_mish(f4 (&acc)[2][4],
                                        const float* __restrict__ gam,
                                        const float* __restrict__ bet,
                                        int wr, int wc, int g, int s,
                                        float (*rowsum)[64][2], float (*rowsq)[64][2],
                                        int buf){
  float gv[4], bev[4];
#pragma unroll
  for (int ct = 0; ct < 4; ++ct){ int n = wc*64 + ct*16 + s; gv[ct] = gam[n]; bev[ct] = bet[n]; }
#pragma unroll
  for (int rt = 0; rt < 2; ++rt)
#pragma unroll
    for (int reg = 0; reg < 4; ++reg){
      float sm = acc[rt][0][reg] + acc[rt][1][reg] + acc[rt][2][reg] + acc[rt][3][reg];
      float sq = acc[rt][0][reg]*acc[rt][0][reg] + acc[rt][1][reg]*acc[rt][1][reg]
               + acc[rt][2][reg]*acc[rt][2][reg] + acc[rt][3][reg]*acc[rt][3][reg];
#pragma unroll
      for (int m = 1; m < 16; m <<= 1){ sm += __shfl_xor(sm, m, 64); sq += __shfl_xor(sq, m, 64); }
      if (s == 0){
        int row = wr*32 + rt*16 + g*4 + reg;
        rowsum[buf][row][wc] = sm; rowsq[buf][row][wc] = sq;
      }
    }
  __syncthreads();
#pragma unroll
  for (int rt = 0; rt < 2; ++rt)
#pragma unroll
    for (int reg = 0; reg < 4; ++reg){
      int row = wr*32 + rt*16 + g*4 + reg;
      float sm = rowsum[buf][row][0] + rowsum[buf][row][1];
      float sq = rowsq[buf][row][0] + rowsq[buf][row][1];
      float mu = sm * (1.f/128.f);
      float var = sq * (1.f/128.f) - mu*mu;
      float rs = rsqrtf(var + 1e-5f);
#pragma unroll
      for (int ct = 0; ct < 4; ++ct)
        acc[rt][ct][reg] = mishf((acc[rt][ct][reg] - mu) * rs * gv[ct] + bev[ct]);
    }
}

__device__ __forceinline__ void write_T(us* Tsh, int wr, int wc, int g, int s,
                                        const f4 (&A)[2][4]){
#pragma unroll
  for (int rt = 0; rt < 2; ++rt)
#pragma unroll
    for (int ct = 0; ct < 4; ++ct)
#pragma unroll
      for (int reg = 0; reg < 4; ++reg){
        int row = wr*32 + rt*16 + g*4 + reg;
        int col = wc*64 + ct*16 + s;
        int byte = row*256 + col*2; byte ^= (row & 7) << 4;
        *(us*)((char*)Tsh + byte) = f2bf(A[rt][ct][reg]);
      }
}

__device__ __forceinline__ void load_a2(const us* Tsh, int wr, int g, int s, bf8 (&a2)[2][4]){
#pragma unroll
  for (int rt = 0; rt < 2; ++rt)
#pragma unroll
    for (int kk = 0; kk < 4; ++kk)
      a2[rt][kk] = lds_frag(Tsh, wr*32 + rt*16 + s, 256, kk*32 + g*8);
}

// ---------- Fused node chains: q, k, m(2 GEMM), b(2 GEMM), c(2 GEMM, no LN) ----------
// NOTE: no aggressive launch_bounds — R3 showed (256,3/4) caps VGPRs below the
// pinned working set and forces scratch spills (WRITE_SIZE +512MB).
__global__ __launch_bounds__(256, 2)
void node_fused(const float* __restrict__ X,
                const us* __restrict__ WqT,  const float* __restrict__ bq,
                const float* __restrict__ gq, const float* __restrict__ beq,
                const us* __restrict__ WkT,  const float* __restrict__ bk,
                const float* __restrict__ gk, const float* __restrict__ bek,
                const us* __restrict__ Wm1T, const float* __restrict__ bm1,
                const float* __restrict__ gm, const float* __restrict__ bem,
                const us* __restrict__ Wm2T, const float* __restrict__ bm2,
                const us* __restrict__ Wb1T, const float* __restrict__ bb1,
                const float* __restrict__ gb, const float* __restrict__ beb,
                const us* __restrict__ Wb2T, const float* __restrict__ bb2,
                const us* __restrict__ Wc1T, const float* __restrict__ bc1,
                const us* __restrict__ Wc2T,
                us* __restrict__ qt, us* __restrict__ kmb, float* __restrict__ xout)
{
  __shared__ us Ash[64 * DN];
  __shared__ float rowsum[2][64][2];
  __shared__ float rowsq[2][64][2];

  const int tid = threadIdx.x;
  const int r0 = blockIdx.x * 64;

  { // stage X rows -> bf16 swizzled LDS (once, shared by 8 GEMMs)
    int r = tid >> 2, c4 = tid & 3;
    int grow = r0 + r; if (grow >= NND) grow = NND - 1;
    const f4* sp = (const f4*)(X + (size_t)grow * DN + c4 * 32);
#pragma unroll
    for (int j = 0; j < 4; ++j){
      f4 v0 = sp[2*j], v1 = sp[2*j+1];
      bf8 o;
#pragma unroll
      for (int q = 0; q < 4; ++q){ o[q] = (short)f2bf(v0[q]); o[4+q] = (short)f2bf(v1[q]); }
      int byte = r*256 + c4*64 + j*16; byte ^= (r & 7) << 4;
      *(bf8*)((char*)Ash + byte) = o;
    }
  }
  __syncthreads();

  const int lane = tid & 63, w = tid >> 6;
  const int wr = w >> 1, wc = w & 1;
  const int g = lane >> 4, s = lane & 15;

  bf8 a[2][4];
#pragma unroll
  for (int rt = 0; rt < 2; ++rt)
#pragma unroll
    for (int kk = 0; kk < 4; ++kk)
      a[rt][kk] = lds_frag(Ash, wr*32 + rt*16 + s, 256, kk*32 + g*8);
  __syncthreads();   // all A-frag reads done -> Ash reusable as T

  f4 acc[2][4], acc2[2][4];
  bf8 a2[2][4];

  // ---- q ----
  gemm_reg(a, WqT, bq, wc, g, s, acc);
  ln_mish(acc, gq, beq, wr, wc, g, s, rowsum, rowsq, 0);
  store_tile<1>((void*)qt, NND, r0, wr, wc, g, s, DN, acc);

  // ---- k ----
  gemm_reg(a, WkT, bk, wc, g, s, acc);
  ln_mish(acc, gk, bek, wr, wc, g, s, rowsum, rowsq, 1);
  store_tile<1>((void*)kmb, NND, r0, wr, wc, g, s, 384, acc);

  // ---- m (2 GEMM) ----
  gemm_reg(a, Wm1T, bm1, wc, g, s, acc);
  ln_mish(acc, gm, bem, wr, wc, g, s, rowsum, rowsq, 0);   // its sync fences k's LN reads + prior Ash reads
  write_T(Ash, wr, wc, g, s, acc);
  __syncthreads();
  load_a2(Ash, wr, g, s, a2);
#pragma unroll
  for (int ct = 0; ct < 4; ++ct){
    float bv = bm2[wc*64 + ct*16 + s]; f4 t = {bv,bv,bv,bv}; acc2[0][ct] = t; acc2[1][ct] = t;
  }
#pragma unroll
  for (int ct = 0; ct < 4; ++ct){
    int n = wc*64 + ct*16 + s;
#pragma unroll
    for (int kk = 0; kk < 4; ++kk){
      bf8 b = gfrag(Wm2T, n, DN, kk*32 + g*8);
      acc2[0][ct] = MFMA16(a2[0][kk], b, acc2[0][ct]);
      acc2[1][ct] = MFMA16(a2[1][kk], b, acc2[1][ct]);
    }
  }
  store_tile<1>((void*)(kmb + 128), NND, r0, wr, wc, g, s, 384, acc2);

  // ---- b (2 GEMM) ----
  gemm_reg(a, Wb1T, bb1, wc, g, s, acc);
  ln_mish(acc, gb, beb, wr, wc, g, s, rowsum, rowsq, 1);   // sync fences m's a2 reads
  write_T(Ash, wr, wc, g, s, acc);
  __syncthreads();
  load_a2(Ash, wr, g, s, a2);
#pragma unroll
  for (int ct = 0; ct < 4; ++ct){
    float bv = bb2[wc*64 + ct*16 + s]; f4 t = {bv,bv,bv,bv}; acc2[0][ct] = t; acc2[1][ct] = t;
  }
#pragma unroll
  for (int ct = 0; ct < 4; ++ct){
    int n = wc*64 + ct*16 + s;
#pragma unroll
    for (int kk = 0; kk < 4; ++kk){
      bf8 b = gfrag(Wb2T, n, DN, kk*32 + g*8);
      acc2[0][ct] = MFMA16(a2[0][kk], b, acc2[0][ct]);
      acc2[1][ct] = MFMA16(a2[1][kk], b, acc2[1][ct]);
    }
  }
  store_tile<1>((void*)(kmb + 256), NND, r0, wr, wc, g, s, 384, acc2);

  // ---- c (2 GEMM, no LN) ----
  gemm_reg(a, Wc1T, bc1, wc, g, s, acc);
#pragma unroll
  for (int rt = 0; rt < 2; ++rt)
#pragma unroll
    for (int ct = 0; ct < 4; ++ct)
#pragma unroll
      for (int reg = 0; reg < 4; ++reg)
        acc[rt][ct][reg] = mishf(acc[rt][ct][reg]);
  __syncthreads();                    // fence b's a2 reads before overwriting Ash
  write_T(Ash, wr, wc, g, s, acc);
  __syncthreads();
  load_a2(Ash, wr, g, s, a2);
#pragma unroll
  for (int ct = 0; ct < 4; ++ct){ f4 t = {0,0,0,0}; acc2[0][ct] = t; acc2[1][ct] = t; }
#pragma unroll
  for (int ct = 0; ct < 4; ++ct){
    int n = wc*64 + ct*16 + s;
#pragma unroll
    for (int kk = 0; kk < 4; ++kk){
      bf8 b = gfrag(Wc2T, n, DN, kk*32 + g*8);
      acc2[0][ct] = MFMA16(a2[0][kk], b, acc2[0][ct]);
      acc2[1][ct] = MFMA16(a2[1][kk], b, acc2[1][ct]);
    }
  }
  store_tile<0>((void*)xout, NND, r0, wr, wc, g, s, DN, acc2);
}

// ---------- CSR build ----------
__global__ void csr_count(const int* __restrict__ dst, int* __restrict__ deg){
  int e = blockIdx.x * 256 + threadIdx.x;
  if (e < NED) atomicAdd(&deg[dst[e]], 1);
}

__global__ __launch_bounds__(1024) void csr_blocksum(const int* __restrict__ deg,
                                                     int* __restrict__ bsum){
  __shared__ int sb[1024];
  int t = threadIdx.x, idx = blockIdx.x * 1024 + t;
  sb[t] = (idx < NND) ? deg[idx] : 0;
  __syncthreads();
  for (int off = 512; off > 0; off >>= 1){
    if (t < off) sb[t] += sb[t + off];
    __syncthreads();
  }
  if (t == 0) bsum[blockIdx.x] = sb[0];
}

__global__ void csr_scanroot(const int* __restrict__ bsum, int* __restrict__ boff,
                             int* __restrict__ ptr){
  if (threadIdx.x == 0){
    int run = 0;
    for (int b = 0; b < NSCAN; ++b){ boff[b] = run; run += bsum[b]; }
    ptr[NND] = run;
  }
}

__global__ __launch_bounds__(1024) void csr_scatter(const int* __restrict__ deg,
                                                    const int* __restrict__ boff,
                                                    int* __restrict__ ptr,
                                                    int* __restrict__ fillctr){
  __shared__ int ss[1024];
  int t = threadIdx.x, idx = blockIdx.x * 1024 + t;
  int v = (idx < NND) ? deg[idx] : 0;
  ss[t] = v;
  __syncthreads();
  for (int off = 1; off < 1024; off <<= 1){
    int x = (t >= off) ? ss[t - off] : 0;
    __syncthreads();
    ss[t] += x;
    __syncthreads();
  }
  if (idx < NND){
    int p = boff[blockIdx.x] + ss[t] - v;
    ptr[idx] = p; fillctr[idx] = p;
  }
}

__global__ void csr_fill(const int* __restrict__ src, const int* __restrict__ dst,
                         int* __restrict__ fillctr,
                         int* __restrict__ ssorted, int* __restrict__ dsorted){
  int e = blockIdx.x * 256 + threadIdx.x;
  if (e < NED){
    int d = dst[e];
    int p = atomicAdd(&fillctr[d], 1);
    ssorted[p] = src[e];
    dsorted[p] = d;
  }
}

// ---------- Edge pass (sorted-by-dst order): rel -> GEMM+LN+mish -> GEMM -> exp -> pbuf + colsum ----------
__global__ __launch_bounds__(256, 2)
void edge_kernel(const us* __restrict__ qtab,
                 const us* __restrict__ kmb,   // [N][384]: k|m|b
                 const us* __restrict__ W1T,
                 const us* __restrict__ W2T,
                 const float* __restrict__ bw1,
                 const float* __restrict__ gwp,
                 const float* __restrict__ bewp,
                 const float* __restrict__ bw2,
                 const int* __restrict__ ssorted,
                 const int* __restrict__ dsorted,
                 us* __restrict__ pbuf,        // [E][128] bf16 = exp(w), sorted order
                 float* __restrict__ colsum)
{
  __shared__ us Ash[64 * DN];                 // staged rel -> T -> p (reused)
  __shared__ float rowsum[1][64][2];
  __shared__ float rowsq[1][64][2];
  __shared__ float csh[DN];

  const int tid = threadIdx.x;
  // XCD-chunked swizzle: 8000 blocks -> each XCD gets a contiguous sorted range
  const int nchunk = gridDim.x >> 3;
  const int swz = (blockIdx.x & 7) * nchunk + (blockIdx.x >> 3);
  const int e0 = swz * 64;
  const int lane = tid & 63, w = tid >> 6;
  const int wr = w >> 1, wc = w & 1;
  const int g = lane >> 4, s = lane & 15;

  if (tid < DN) csh[tid] = 0.f;

  // register-pinned weight fragments (per wave)
  bf8 B1[4][4], B2[4][4];
  float b1v[4], gv[4], bev[4], b2v[4];
#pragma unroll
  for (int ct = 0; ct < 4; ++ct){
    int n = wc*64 + ct*16 + s;
#pragma unroll
    for (int kk = 0; kk < 4; ++kk){
      B1[ct][kk] = gfrag(W1T, n, DN, kk*32 + g*8);
      B2[ct][kk] = gfrag(W2T, n, DN, kk*32 + g*8);
    }
    b1v[ct] = bw1[n]; gv[ct] = gwp[n]; bev[ct] = bewp[n]; b2v[ct] = bw2[n];
  }

  { // gather + rel construction -> Ash
    int r = tid >> 2, c4 = tid & 3;
    int e = e0 + r;
    int sn = ssorted[e], dn = dsorted[e];
    const bf8* qp = (const bf8*)(qtab + (size_t)sn * DN + c4 * 32);
    const us* kb = kmb + (size_t)dn * 384 + c4 * 32;
    float rel[32]; float ss = 0.f;
#pragma unroll
    for (int j = 0; j < 4; ++j){
      bf8 qv = qp[j];
      bf8 kv = *(const bf8*)(kb + j*8);
#pragma unroll
      for (int q = 0; q < 8; ++q){
        float d = bf2f((us)qv[q]) - bf2f((us)kv[q]);
        rel[j*8+q] = d; ss += d * d;
      }
    }
    ss += __shfl_xor(ss, 1, 64);
    ss += __shfl_xor(ss, 2, 64);
    float rinv = rsqrtf(ss + 1e-8f);
#pragma unroll
    for (int j = 0; j < 4; ++j){
      bf8 mv = *(const bf8*)(kb + 128 + j*8);
      bf8 bv = *(const bf8*)(kb + 256 + j*8);
      bf8 o;
#pragma unroll
      for (int q = 0; q < 8; ++q){
        float v = rel[j*8+q] * rinv * bf2f((us)mv[q]) + bf2f((us)bv[q]);
        o[q] = (short)f2bf(v);
      }
      int byte = r*256 + c4*64 + j*16; byte ^= (r & 7) << 4;
      *(bf8*)((char*)Ash + byte) = o;
    }
  }
  __syncthreads();   // (1)

  // GEMM1 from Ash
  f4 acc[2][4];
#pragma unroll
  for (int ct = 0; ct < 4; ++ct){ f4 t = {b1v[ct], b1v[ct], b1v[ct], b1v[ct]}; acc[0][ct] = t; acc[1][ct] = t; }
  bf8 a[2][4];
#pragma unroll
  for (int rt = 0; rt < 2; ++rt)
#pragma unroll
    for (int kk = 0; kk < 4; ++kk)
      a[rt][kk] = lds_frag(Ash, wr*32 + rt*16 + s, 256, kk*32 + g*8);
#pragma unroll
  for (int ct = 0; ct < 4; ++ct)
#pragma unroll
    for (int kk = 0; kk < 4; ++kk){
      acc[0][ct] = MFMA16(a[0][kk], B1[ct][kk], acc[0][ct]);
      acc[1][ct] = MFMA16(a[1][kk], B1[ct][kk], acc[1][ct]);
    }

  // LN + mish (internal sync (2) fences all Ash A-frag reads)
#pragma unroll
  for (int rt = 0; rt < 2; ++rt)
#pragma unroll
    for (int reg = 0; reg < 4; ++reg){
      float sm = acc[rt][0][reg] + acc[rt][1][reg] + acc[rt][2][reg] + acc[rt][3][reg];
      float sq = acc[rt][0][reg]*acc[rt][0][reg] + acc[rt][1][reg]*acc[rt][1][reg]
               + acc[rt][2][reg]*acc[rt][2][reg] + acc[rt][3][reg]*acc[rt][3][reg];
#pragma unroll
      for (int m = 1; m < 16; m <<= 1){ sm += __shfl_xor(sm, m, 64); sq += __shfl_xor(sq, m, 64); }
      if (s == 0){
        int row = wr*32 + rt*16 + g*4 + reg;
        rowsum[0][row][wc] = sm; rowsq[0][row][wc] = sq;
      }
    }
  __syncthreads();   // (2)
#pragma unroll
  for (int rt = 0; rt < 2; ++rt)
#pragma unroll
    for (int reg = 0; reg < 4; ++reg){
      int row = wr*32 + rt*16 + g*4 + reg;
      float sm = rowsum[0][row][0] + rowsum[0][row][1];
      float sq = rowsq[0][row][0] + rowsq[0][row][1];
      float mu = sm * (1.f/128.f);
      float var = sq * (1.f/128.f) - mu*mu;
      float rs = rsqrtf(var + 1e-5f);
#pragma unroll
      for (int ct = 0; ct < 4; ++ct)
        acc[rt][ct][reg] = mishf((acc[rt][ct][reg] - mu) * rs * gv[ct] + bev[ct]);
    }

  // T -> Ash (reuse)
  write_T(Ash, wr, wc, g, s, acc);
  __syncthreads();   // (3)

  // GEMM2 -> p = exp(w)
  f4 p[2][4];
#pragma unroll
  for (int ct = 0; ct < 4; ++ct){ f4 t = {b2v[ct], b2v[ct], b2v[ct], b2v[ct]}; p[0][ct] = t; p[1][ct] = t; }
  bf8 a2[2][4];
  load_a2(Ash, wr, g, s, a2);
#pragma unroll
  for (int ct = 0; ct < 4; ++ct)
#pragma unroll
    for (int kk = 0; kk < 4; ++kk){
      p[0][ct] = MFMA16(a2[0][kk], B2[ct][kk], p[0][ct]);
      p[1][ct] = MFMA16(a2[1][kk], B2[ct][kk], p[1][ct]);
    }
#pragma unroll
  for (int rt = 0; rt < 2; ++rt)
#pragma unroll
    for (int ct = 0; ct < 4; ++ct)
#pragma unroll
      for (int reg = 0; reg < 4; ++reg)
        p[rt][ct][reg] = __expf(p[rt][ct][reg]);

  // per-column partial sums
#pragma unroll
  for (int ct = 0; ct < 4; ++ct){
    float cp = 0.f;
#pragma unroll
    for (int rt = 0; rt < 2; ++rt)
#pragma unroll
      for (int reg = 0; reg < 4; ++reg) cp += p[rt][ct][reg];
    cp += __shfl_xor(cp, 16, 64);
    cp += __shfl_xor(cp, 32, 64);
    if (g == 0) atomicAdd(&csh[wc*64 + ct*16 + s], cp);
  }
  __syncthreads();   // (4) a2 reads + csh adds done

  // p -> Ash (bf16, swizzled) for coalesced global store
  write_T(Ash, wr, wc, g, s, p);
  __syncthreads();   // (5)

  { // coalesced 16B stores: 64 rows x 256B, sorted position
    int r = tid >> 2, c4 = tid & 3;
    us* dp = pbuf + (size_t)(e0 + r) * DN + c4 * 32;
#pragma unroll
    for (int j = 0; j < 4; ++j){
      int byte = r*256 + c4*64 + j*16; byte ^= (r & 7) << 4;
      bf8 v = *(const bf8*)((const char*)Ash + byte);
      *(bf8*)(dp + j*8) = v;
    }
  }
  if (tid < DN) atomicAdd(&colsum[tid], csh[tid]);
}

// ---------- final: h_neigh gather (sequential CSR range) + concat GEMMs ----------
__global__ __launch_bounds__(256, 2)
void final_h(const float* __restrict__ nodef,
             const us* __restrict__ pbuf,
             const int* __restrict__ ptr,
             const float* __restrict__ colsum,
             const us* __restrict__ Wn1T,
             const float* __restrict__ bn1,
             const us* __restrict__ Wn2T,
             const float* __restrict__ bn2,
             float* __restrict__ outh)
{
  __shared__ us Ash[64 * 256];   // [64 rows][256 cols] bf16, stride 512B

  const int tid = threadIdx.x;
  const int r0 = blockIdx.x * 64;
  const int lane = tid & 63, w = tid >> 6;

  { // stage node_feat rows -> cols 0..127
    int r = tid >> 2, c4 = tid & 3;
    int grow = r0 + r; if (grow >= NND) grow = NND - 1;
    const f4* np = (const f4*)(nodef + (size_t)grow * DN + c4 * 32);
#pragma unroll
    for (int j = 0; j < 4; ++j){
      f4 v0 = np[2*j], v1 = np[2*j+1];
      bf8 o;
#pragma unroll
      for (int q = 0; q < 4; ++q){ o[q] = (short)f2bf(v0[q]); o[4+q] = (short)f2bf(v1[q]); }
      int byte = r*512 + c4*64 + j*16; byte ^= (r & 7) << 4;
      *(bf8*)((char*)Ash + byte) = o;
    }
  }

  { // gather h_neigh (sequential pbuf rows per node) -> cols 128..255
    float c0 = colsum[lane*2], c1 = colsum[lane*2 + 1];
    for (int i = 0; i < 16; ++i){
      int lr = w*16 + i;
      int n = r0 + lr;
      float a0 = 0.f, a1 = 0.f;
      if (n < NND){
        int beg = ptr[n], end = ptr[n+1];
        for (int e = beg; e < end; ++e){
          unsigned int v = *(const unsigned int*)(pbuf + (size_t)e * DN + lane * 2);
          a0 += bf2f((us)(v & 0xffffu));
          a1 += bf2f((us)(v >> 16));
        }
      }
      unsigned int o = ((unsigned int)f2bf(a1 / c1) << 16) | (unsigned int)f2bf(a0 / c0);
      int byte = lr*512 + 256 + lane*4; byte ^= (lr & 7) << 4;
      *(unsigned int*)((char*)Ash + byte) = o;
    }
  }
  __syncthreads();

  const int wr = w >> 1, wc = w & 1;
  const int g = lane >> 4, s = lane & 15;

  float b1v[4], b2v[4];
#pragma unroll
  for (int ct = 0; ct < 4; ++ct){ int n = wc*64 + ct*16 + s; b1v[ct] = bn1[n]; b2v[ct] = bn2[n]; }

  f4 acc[2][4];
#pragma unroll
  for (int ct = 0; ct < 4; ++ct){ f4 t = {b1v[ct], b1v[ct], b1v[ct], b1v[ct]}; acc[0][ct] = t; acc[1][ct] = t; }

  bf8 a[2][8];
#pragma unroll
  for (int rt = 0; rt < 2; ++rt)
#pragma unroll
    for (int kk = 0; kk < 8; ++kk)
      a[rt][kk] = lds_frag(Ash, wr*32 + rt*16 + s, 512, kk*32 + g*8);
  __syncthreads();   // frag reads done -> Ash reusable as T

#pragma unroll
  for (int ct = 0; ct < 4; ++ct){
    int n = wc*64 + ct*16 + s;
#pragma unroll
    for (int kk = 0; kk < 8; ++kk){
      bf8 b = gfrag(Wn1T, n, 256, kk*32 + g*8);
      acc[0][ct] = MFMA16(a[0][kk], b, acc[0][ct]);
      acc[1][ct] = MFMA16(a[1][kk], b, acc[1][ct]);
    }
  }

#pragma unroll
  for (int rt = 0; rt < 2; ++rt)
#pragma unroll
    for (int ct = 0; ct < 4; ++ct)
#pragma unroll
      for (int reg = 0; reg < 4; ++reg)
        acc[rt][ct][reg] = mishf(acc[rt][ct][reg]);
  write_T((us*)Ash, wr, wc, g, s, acc);
  __syncthreads();

  f4 acc2[2][4];
#pragma unroll
  for (int ct = 0; ct < 4; ++ct){ f4 t = {b2v[ct], b2v[ct], b2v[ct], b2v[ct]}; acc2[0][ct] = t; acc2[1][ct] = t; }
  bf8 a2[2][4];
  load_a2((const us*)Ash, wr, g, s, a2);
#pragma unroll
  for (int ct = 0; ct < 4; ++ct){
    int n = wc*64 + ct*16 + s;
#pragma unroll
    for (int kk = 0; kk < 4; ++kk){
      bf8 b = gfrag(Wn2T, n, DN, kk*32 + g*8);
      acc2[0][ct] = MFMA16(a2[0][kk], b, acc2[0][ct]);
      acc2[1][ct] = MFMA16(a2[1][kk], b, acc2[1][ct]);
    }
  }
  store_tile<0>((void*)outh, NND, r0, wr, wc, g, s, DN, acc2);
}

struct WPrepArgs {
  const float* w[12];
  us* wt[12];
  int K[12];
};

// W^T bf16: wt[n*K + k] = bf16(W[k*128 + n])
__global__ void prep_weights(WPrepArgs a){
  int widx = blockIdx.y;
  int K = a.K[widx];
  int idx = blockIdx.x * 256 + threadIdx.x;
  if (idx >= DN * K) return;
  int kshift = (K == 256) ? 8 : 7;
  int n = idx >> kshift;
  int k = idx & (K - 1);
  a.wt[widx][idx] = f2bf(a.w[widx][(size_t)k * DN + n]);
}

extern "C" void kernel_launch(void* const* d_in, const int* in_sizes, int n_in,
                              void* d_out, int out_size, void* d_ws, size_t ws_size,
                              hipStream_t stream) {
  const float* node_feat = (const float*)d_in[0];
  const float* coordf    = (const float*)d_in[1];
  const float* Wq  = (const float*)d_in[2];
  const float* bq  = (const float*)d_in[3];
  const float* gq  = (const float*)d_in[4];
  const float* beq = (const float*)d_in[5];
  const float* Wk  = (const float*)d_in[6];
  const float* bk  = (const float*)d_in[7];
  const float* gk  = (const float*)d_in[8];
  const float* bek = (const float*)d_in[9];
  const float* Wm1 = (const float*)d_in[10];
  const float* bm1 = (const float*)d_in[11];
  const float* gm  = (const float*)d_in[12];
  const float* bem = (const float*)d_in[13];
  const float* Wm2 = (const float*)d_in[14];
  const float* bm2 = (const float*)d_in[15];
  const float* Wb1 = (const float*)d_in[16];
  const float* bb1 = (const float*)d_in[17];
  const float* gb  = (const float*)d_in[18];
  const float* beb = (const float*)d_in[19];
  const float* Wb2 = (const float*)d_in[20];
  const float* bb2 = (const float*)d_in[21];
  const float* Ww1 = (const float*)d_in[22];
  const float* bw1 = (const float*)d_in[23];
  const float* gw  = (const float*)d_in[24];
  const float* bew = (const float*)d_in[25];
  const float* Ww2 = (const float*)d_in[26];
  const float* bw2 = (const float*)d_in[27];
  const float* Wn1 = (const float*)d_in[28];
  const float* bn1 = (const float*)d_in[29];
  const float* Wn2 = (const float*)d_in[30];
  const float* bn2 = (const float*)d_in[31];
  const float* Wc1 = (const float*)d_in[32];
  const float* bc1 = (const float*)d_in[33];
  const float* Wc2 = (const float*)d_in[34];
  const int* srcI  = (const int*)d_in[35];
  const int* dstI  = (const int*)d_in[36];

  char* ws = (char*)d_ws;
  size_t off = 0;
  auto alloc = [&](size_t bytes) -> char* {
    char* p = ws + off;
    off += (bytes + 255) & ~(size_t)255;
    return p;
  };
  us*    qt      = (us*)alloc((size_t)NND * DN * 2);
  us*    kmb     = (us*)alloc((size_t)NND * 384 * 2);
  us*    pbuf    = (us*)alloc((size_t)NED * DN * 2);
  float* colsum  = (float*)alloc(DN * 4);
  int*   deg     = (int*)alloc((size_t)NND * 4);
  int*   ptr     = (int*)alloc((size_t)(NND + 1) * 4);
  int*   fillctr = (int*)alloc((size_t)NND * 4);
  int*   ssorted = (int*)alloc((size_t)NED * 4);
  int*   dsorted = (int*)alloc((size_t)NED * 4);
  int*   bsum    = (int*)alloc((size_t)NSCAN * 4);
  int*   boff    = (int*)alloc((size_t)NSCAN * 4);
  us*    wtb     = (us*)alloc((size_t)12 * 16384 * 2);

  hipMemsetAsync(colsum, 0, DN * 4, stream);
  hipMemsetAsync(deg, 0, (size_t)NND * 4, stream);

  WPrepArgs pa;
  const float* wsrc[12] = {Wq, Wk, Wm1, Wm2, Wb1, Wb2, Ww1, Ww2, Wc1, Wc2, Wn2, Wn1};
  for (int i = 0; i < 12; ++i){
    pa.w[i] = wsrc[i];
    pa.wt[i] = wtb + (size_t)i * 16384;
    pa.K[i] = (i == 11) ? 256 : 128;
  }
  prep_weights<<<dim3(128, 12), 256, 0, stream>>>(pa);

  // CSR build + edge sort by dst
  csr_count<<<(NED + 255) / 256, 256, 0, stream>>>(dstI, deg);
  csr_blocksum<<<NSCAN, 1024, 0, stream>>>(deg, bsum);
  csr_scanroot<<<1, 64, 0, stream>>>(bsum, boff, ptr);
  csr_scatter<<<NSCAN, 1024, 0, stream>>>(deg, boff, ptr, fillctr);
  csr_fill<<<(NED + 255) / 256, 256, 0, stream>>>(srcI, dstI, fillctr, ssorted, dsorted);

  const int NB = (NND + 63) / 64;  // 782

  node_fused<<<NB, 256, 0, stream>>>(coordf,
      pa.wt[0], bq, gq, beq,
      pa.wt[1], bk, gk, bek,
      pa.wt[2], bm1, gm, bem, pa.wt[3], bm2,
      pa.wt[4], bb1, gb, beb, pa.wt[5], bb2,
      pa.wt[8], bc1, pa.wt[9],
      qt, kmb, (float*)d_out + (size_t)NND * DN);

  edge_kernel<<<NED / 64, 256, 0, stream>>>(qt, kmb, pa.wt[6], pa.wt[7],
                                            bw1, gw, bew, bw2, ssorted, dsorted, pbuf, colsum);

  final_h<<<NB, 256, 0, stream>>>(node_feat, pbuf, ptr, colsum,
                                  pa.wt[11], bn1, pa.wt[10], bn2, (float*)d_out);
}

// Round 5
// 517.111 us; speedup vs baseline: 1.4165x; 1.1628x over previous
//
#include <hip/hip_runtime.h>
#include <cstdint>
#include <cstddef>

#define DN 128
#define NND 50000
#define NED 512000
#define NSCAN 49   // ceil(NND/1024)

typedef __attribute__((ext_vector_type(8))) short bf8;
typedef __attribute__((ext_vector_type(4))) float f4;
typedef unsigned short us;

__device__ __forceinline__ us f2bf(float f){
  union { float f; unsigned int u; } c; c.f = f;
  unsigned int r = c.u + 0x7fffu + ((c.u >> 16) & 1u);
  return (us)(r >> 16);
}
__device__ __forceinline__ float bf2f(us u){
  union { unsigned int u; float f; } c; c.u = ((unsigned int)u) << 16;
  return c.f;
}
// mish(x) = x*tanh(softplus(x)) = x*(u^2-1)/(u^2+1), u = 1+exp(x)
__device__ __forceinline__ float mishf(float x){
  float e = __expf(x);
  float u = 1.f + e;
  float u2 = u * u;
  float t = (u2 - 1.f) / (u2 + 1.f);
  return x * ((x > 20.f) ? 1.f : t);
}

#define MFMA16(a, b, c) __builtin_amdgcn_mfma_f32_16x16x32_bf16((a), (b), (c), 0, 0, 0)

// LDS fragment read: row-major [rows][K] bf16 with (row&7)<<4 byte XOR swizzle.
__device__ __forceinline__ bf8 lds_frag(const us* base, int row, int rowStrideB, int kElem){
  int byte = row * rowStrideB + kElem * 2;
  byte ^= (row & 7) << 4;
  return *(const bf8*)((const char*)base + byte);
}
// Global weight fragment: W^T stored [Nout][K] bf16, plain row-major.
__device__ __forceinline__ bf8 gfrag(const us* W, int n, int K, int kElem){
  return *(const bf8*)(W + (size_t)n * K + kElem);
}

template<int OUT_BF16>
__device__ __forceinline__ void store_tile(void* outp, int nrows, int r0,
                                           int wr, int wc, int g, int s, int ostride,
                                           const f4 (&A)[2][4]){
#pragma unroll
  for (int rt = 0; rt < 2; ++rt)
#pragma unroll
    for (int ct = 0; ct < 4; ++ct)
#pragma unroll
      for (int reg = 0; reg < 4; ++reg){
        int row = r0 + wr*32 + rt*16 + g*4 + reg;
        if (row < nrows){
          int col = wc*64 + ct*16 + s;
          float v = A[rt][ct][reg];
          if constexpr (OUT_BF16 != 0)
            ((us*)outp)[(size_t)row*ostride + col] = f2bf(v);
          else
            ((float*)outp)[(size_t)row*ostride + col] = v;
        }
      }
}

// GEMM1: acc = bias + A(regs) @ W^T
__device__ __forceinline__ void gemm_reg(const bf8 (&a)[2][4], const us* __restrict__ WT,
                                         const float* __restrict__ bias,
                                         int wc, int g, int s, f4 (&acc)[2][4]){
#pragma unroll
  for (int ct = 0; ct < 4; ++ct){
    float bv = bias ? bias[wc*64 + ct*16 + s] : 0.f;
    f4 t = {bv, bv, bv, bv};
    acc[0][ct] = t; acc[1][ct] = t;
  }
#pragma unroll
  for (int ct = 0; ct < 4; ++ct){
    int n = wc*64 + ct*16 + s;
#pragma unroll
    for (int kk = 0; kk < 4; ++kk){
      bf8 b = gfrag(WT, n, DN, kk*32 + g*8);
      acc[0][ct] = MFMA16(a[0][kk], b, acc[0][ct]);
      acc[1][ct] = MFMA16(a[1][kk], b, acc[1][ct]);
    }
  }
}

// LN across the 128-wide row (two waves share a row) + mish. Uses buf parity to
// avoid WAR races on the stats arrays between consecutive chains.
__device__ __forceinline__ void ln_mish(f4 (&acc)[2][4],
                                        const float* __restrict__ gam,
                                        const float* __restrict__ bet,
                                        int wr, int wc, int g, int s,
                                        float (*rowsum)[64][2], float (*rowsq)[64][2],
                                        int buf){
  float gv[4], bev[4];
#pragma unroll
  for (int ct = 0; ct < 4; ++ct){ int n = wc*64 + ct*16 + s; gv[ct] = gam[n]; bev[ct] = bet[n]; }
#pragma unroll
  for (int rt = 0; rt < 2; ++rt)
#pragma unroll
    for (int reg = 0; reg < 4; ++reg){
      float sm = acc[rt][0][reg] + acc[rt][1][reg] + acc[rt][2][reg] + acc[rt][3][reg];
      float sq = acc[rt][0][reg]*acc[rt][0][reg] + acc[rt][1][reg]*acc[rt][1][reg]
               + acc[rt][2][reg]*acc[rt][2][reg] + acc[rt][3][reg]*acc[rt][3][reg];
#pragma unroll
      for (int m = 1; m < 16; m <<= 1){ sm += __shfl_xor(sm, m, 64); sq += __shfl_xor(sq, m, 64); }
      if (s == 0){
        int row = wr*32 + rt*16 + g*4 + reg;
        rowsum[buf][row][wc] = sm; rowsq[buf][row][wc] = sq;
      }
    }
  __syncthreads();
#pragma unroll
  for (int rt = 0; rt < 2; ++rt)
#pragma unroll
    for (int reg = 0; reg < 4; ++reg){
      int row = wr*32 + rt*16 + g*4 + reg;
      float sm = rowsum[buf][row][0] + rowsum[buf][row][1];
      float sq = rowsq[buf][row][0] + rowsq[buf][row][1];
      float mu = sm * (1.f/128.f);
      float var = sq * (1.f/128.f) - mu*mu;
      float rs = rsqrtf(var + 1e-5f);
#pragma unroll
      for (int ct = 0; ct < 4; ++ct)
        acc[rt][ct][reg] = mishf((acc[rt][ct][reg] - mu) * rs * gv[ct] + bev[ct]);
    }
}

__device__ __forceinline__ void write_T(us* Tsh, int wr, int wc, int g, int s,
                                        const f4 (&A)[2][4]){
#pragma unroll
  for (int rt = 0; rt < 2; ++rt)
#pragma unroll
    for (int ct = 0; ct < 4; ++ct)
#pragma unroll
      for (int reg = 0; reg < 4; ++reg){
        int row = wr*32 + rt*16 + g*4 + reg;
        int col = wc*64 + ct*16 + s;
        int byte = row*256 + col*2; byte ^= (row & 7) << 4;
        *(us*)((char*)Tsh + byte) = f2bf(A[rt][ct][reg]);
      }
}

__device__ __forceinline__ void load_a2(const us* Tsh, int wr, int g, int s, bf8 (&a2)[2][4]){
#pragma unroll
  for (int rt = 0; rt < 2; ++rt)
#pragma unroll
    for (int kk = 0; kk < 4; ++kk)
      a2[rt][kk] = lds_frag(Tsh, wr*32 + rt*16 + s, 256, kk*32 + g*8);
}

// ---------- Fused node chains: q, k, m(2 GEMM), b(2 GEMM), c(2 GEMM, no LN) ----------
// NOTE: min-waves arg stays at 2 — R3 showed higher values cap VGPRs below the
// pinned working set and force scratch spills (WRITE_SIZE +512MB).
__global__ __launch_bounds__(256, 2)
void node_fused(const float* __restrict__ X,
                const us* __restrict__ WqT,  const float* __restrict__ bq,
                const float* __restrict__ gq, const float* __restrict__ beq,
                const us* __restrict__ WkT,  const float* __restrict__ bk,
                const float* __restrict__ gk, const float* __restrict__ bek,
                const us* __restrict__ Wm1T, const float* __restrict__ bm1,
                const float* __restrict__ gm, const float* __restrict__ bem,
                const us* __restrict__ Wm2T, const float* __restrict__ bm2,
                const us* __restrict__ Wb1T, const float* __restrict__ bb1,
                const float* __restrict__ gb, const float* __restrict__ beb,
                const us* __restrict__ Wb2T, const float* __restrict__ bb2,
                const us* __restrict__ Wc1T, const float* __restrict__ bc1,
                const us* __restrict__ Wc2T,
                us* __restrict__ qt, us* __restrict__ kmb, float* __restrict__ xout)
{
  __shared__ us Ash[64 * DN];
  __shared__ float rowsum[2][64][2];
  __shared__ float rowsq[2][64][2];

  const int tid = threadIdx.x;
  const int r0 = blockIdx.x * 64;

  { // stage X rows -> bf16 swizzled LDS (once, shared by 8 GEMMs)
    int r = tid >> 2, c4 = tid & 3;
    int grow = r0 + r; if (grow >= NND) grow = NND - 1;
    const f4* sp = (const f4*)(X + (size_t)grow * DN + c4 * 32);
#pragma unroll
    for (int j = 0; j < 4; ++j){
      f4 v0 = sp[2*j], v1 = sp[2*j+1];
      bf8 o;
#pragma unroll
      for (int q = 0; q < 4; ++q){ o[q] = (short)f2bf(v0[q]); o[4+q] = (short)f2bf(v1[q]); }
      int byte = r*256 + c4*64 + j*16; byte ^= (r & 7) << 4;
      *(bf8*)((char*)Ash + byte) = o;
    }
  }
  __syncthreads();

  const int lane = tid & 63, w = tid >> 6;
  const int wr = w >> 1, wc = w & 1;
  const int g = lane >> 4, s = lane & 15;

  bf8 a[2][4];
#pragma unroll
  for (int rt = 0; rt < 2; ++rt)
#pragma unroll
    for (int kk = 0; kk < 4; ++kk)
      a[rt][kk] = lds_frag(Ash, wr*32 + rt*16 + s, 256, kk*32 + g*8);
  __syncthreads();   // all A-frag reads done -> Ash reusable as T

  f4 acc[2][4], acc2[2][4];
  bf8 a2[2][4];

  // ---- q ----
  gemm_reg(a, WqT, bq, wc, g, s, acc);
  ln_mish(acc, gq, beq, wr, wc, g, s, rowsum, rowsq, 0);
  store_tile<1>((void*)qt, NND, r0, wr, wc, g, s, DN, acc);

  // ---- k ----
  gemm_reg(a, WkT, bk, wc, g, s, acc);
  ln_mish(acc, gk, bek, wr, wc, g, s, rowsum, rowsq, 1);
  store_tile<1>((void*)kmb, NND, r0, wr, wc, g, s, 384, acc);

  // ---- m (2 GEMM) ----
  gemm_reg(a, Wm1T, bm1, wc, g, s, acc);
  ln_mish(acc, gm, bem, wr, wc, g, s, rowsum, rowsq, 0);   // its sync fences k's LN reads + prior Ash reads
  write_T(Ash, wr, wc, g, s, acc);
  __syncthreads();
  load_a2(Ash, wr, g, s, a2);
#pragma unroll
  for (int ct = 0; ct < 4; ++ct){
    float bv = bm2[wc*64 + ct*16 + s]; f4 t = {bv,bv,bv,bv}; acc2[0][ct] = t; acc2[1][ct] = t;
  }
#pragma unroll
  for (int ct = 0; ct < 4; ++ct){
    int n = wc*64 + ct*16 + s;
#pragma unroll
    for (int kk = 0; kk < 4; ++kk){
      bf8 b = gfrag(Wm2T, n, DN, kk*32 + g*8);
      acc2[0][ct] = MFMA16(a2[0][kk], b, acc2[0][ct]);
      acc2[1][ct] = MFMA16(a2[1][kk], b, acc2[1][ct]);
    }
  }
  store_tile<1>((void*)(kmb + 128), NND, r0, wr, wc, g, s, 384, acc2);

  // ---- b (2 GEMM) ----
  gemm_reg(a, Wb1T, bb1, wc, g, s, acc);
  ln_mish(acc, gb, beb, wr, wc, g, s, rowsum, rowsq, 1);   // sync fences m's a2 reads
  write_T(Ash, wr, wc, g, s, acc);
  __syncthreads();
  load_a2(Ash, wr, g, s, a2);
#pragma unroll
  for (int ct = 0; ct < 4; ++ct){
    float bv = bb2[wc*64 + ct*16 + s]; f4 t = {bv,bv,bv,bv}; acc2[0][ct] = t; acc2[1][ct] = t;
  }
#pragma unroll
  for (int ct = 0; ct < 4; ++ct){
    int n = wc*64 + ct*16 + s;
#pragma unroll
    for (int kk = 0; kk < 4; ++kk){
      bf8 b = gfrag(Wb2T, n, DN, kk*32 + g*8);
      acc2[0][ct] = MFMA16(a2[0][kk], b, acc2[0][ct]);
      acc2[1][ct] = MFMA16(a2[1][kk], b, acc2[1][ct]);
    }
  }
  store_tile<1>((void*)(kmb + 256), NND, r0, wr, wc, g, s, 384, acc2);

  // ---- c (2 GEMM, no LN) ----
  gemm_reg(a, Wc1T, bc1, wc, g, s, acc);
#pragma unroll
  for (int rt = 0; rt < 2; ++rt)
#pragma unroll
    for (int ct = 0; ct < 4; ++ct)
#pragma unroll
      for (int reg = 0; reg < 4; ++reg)
        acc[rt][ct][reg] = mishf(acc[rt][ct][reg]);
  __syncthreads();                    // fence b's a2 reads before overwriting Ash
  write_T(Ash, wr, wc, g, s, acc);
  __syncthreads();
  load_a2(Ash, wr, g, s, a2);
#pragma unroll
  for (int ct = 0; ct < 4; ++ct){ f4 t = {0,0,0,0}; acc2[0][ct] = t; acc2[1][ct] = t; }
#pragma unroll
  for (int ct = 0; ct < 4; ++ct){
    int n = wc*64 + ct*16 + s;
#pragma unroll
    for (int kk = 0; kk < 4; ++kk){
      bf8 b = gfrag(Wc2T, n, DN, kk*32 + g*8);
      acc2[0][ct] = MFMA16(a2[0][kk], b, acc2[0][ct]);
      acc2[1][ct] = MFMA16(a2[1][kk], b, acc2[1][ct]);
    }
  }
  store_tile<0>((void*)xout, NND, r0, wr, wc, g, s, DN, acc2);
}

// ---------- CSR build ----------
__global__ void csr_count(const int* __restrict__ dst, int* __restrict__ deg){
  int e = blockIdx.x * 256 + threadIdx.x;
  if (e < NED) atomicAdd(&deg[dst[e]], 1);
}

__global__ __launch_bounds__(1024) void csr_blocksum(const int* __restrict__ deg,
                                                     int* __restrict__ bsum){
  __shared__ int sb[1024];
  int t = threadIdx.x, idx = blockIdx.x * 1024 + t;
  sb[t] = (idx < NND) ? deg[idx] : 0;
  __syncthreads();
  for (int off = 512; off > 0; off >>= 1){
    if (t < off) sb[t] += sb[t + off];
    __syncthreads();
  }
  if (t == 0) bsum[blockIdx.x] = sb[0];
}

__global__ void csr_scanroot(const int* __restrict__ bsum, int* __restrict__ boff){
  if (threadIdx.x == 0){
    int run = 0;
    for (int b = 0; b < NSCAN; ++b){ boff[b] = run; run += bsum[b]; }
  }
}

__global__ __launch_bounds__(1024) void csr_scatter(const int* __restrict__ deg,
                                                    const int* __restrict__ boff,
                                                    int* __restrict__ fillctr){
  __shared__ int ss[1024];
  int t = threadIdx.x, idx = blockIdx.x * 1024 + t;
  int v = (idx < NND) ? deg[idx] : 0;
  ss[t] = v;
  __syncthreads();
  for (int off = 1; off < 1024; off <<= 1){
    int x = (t >= off) ? ss[t - off] : 0;
    __syncthreads();
    ss[t] += x;
    __syncthreads();
  }
  if (idx < NND){
    int p = boff[blockIdx.x] + ss[t] - v;
    fillctr[idx] = p;
  }
}

__global__ void csr_fill(const int* __restrict__ src, const int* __restrict__ dst,
                         int* __restrict__ fillctr,
                         int* __restrict__ ssorted, int* __restrict__ dsorted){
  int e = blockIdx.x * 256 + threadIdx.x;
  if (e < NED){
    int d = dst[e];
    int p = atomicAdd(&fillctr[d], 1);
    ssorted[p] = src[e];
    dsorted[p] = d;
  }
}

// ---------- Edge pass (sorted-by-dst): rel -> GEMM+LN+mish -> GEMM -> exp ->
// block-level segment-sum by dst -> atomic h accumulate + per-chunk colsum ----------
__global__ __launch_bounds__(256, 2)
void edge_kernel(const us* __restrict__ qtab,
                 const us* __restrict__ kmb,   // [N][384]: k|m|b
                 const us* __restrict__ W1T,
                 const us* __restrict__ W2T,
                 const float* __restrict__ bw1,
                 const float* __restrict__ gwp,
                 const float* __restrict__ bewp,
                 const float* __restrict__ bw2,
                 const int* __restrict__ ssorted,
                 const int* __restrict__ dsorted,
                 float* __restrict__ hacc,      // [N][128] f32, atomic accumulate
                 float* __restrict__ colsum8)   // [8][128] f32, per-XCD-chunk slices
{
  __shared__ us Ash[64 * DN];                 // staged rel -> T -> p (reused)
  __shared__ float rowsum[1][64][2];
  __shared__ float rowsq[1][64][2];
  __shared__ int dsh[64];

  const int tid = threadIdx.x;
  // XCD-chunked swizzle: 8000 blocks -> each XCD gets a contiguous sorted range
  const int nchunk = gridDim.x >> 3;
  const int swz = (blockIdx.x & 7) * nchunk + (blockIdx.x >> 3);
  const int e0 = swz * 64;
  const int lane = tid & 63, w = tid >> 6;
  const int wr = w >> 1, wc = w & 1;
  const int g = lane >> 4, s = lane & 15;

  if (tid < 64) dsh[tid] = dsorted[e0 + tid];

  // register-pinned weight fragments (per wave)
  bf8 B1[4][4], B2[4][4];
  float b1v[4], gv[4], bev[4], b2v[4];
#pragma unroll
  for (int ct = 0; ct < 4; ++ct){
    int n = wc*64 + ct*16 + s;
#pragma unroll
    for (int kk = 0; kk < 4; ++kk){
      B1[ct][kk] = gfrag(W1T, n, DN, kk*32 + g*8);
      B2[ct][kk] = gfrag(W2T, n, DN, kk*32 + g*8);
    }
    b1v[ct] = bw1[n]; gv[ct] = gwp[n]; bev[ct] = bewp[n]; b2v[ct] = bw2[n];
  }

  { // gather + rel construction -> Ash
    int r = tid >> 2, c4 = tid & 3;
    int e = e0 + r;
    int sn = ssorted[e], dn = dsorted[e];
    const bf8* qp = (const bf8*)(qtab + (size_t)sn * DN + c4 * 32);
    const us* kb = kmb + (size_t)dn * 384 + c4 * 32;
    float rel[32]; float ss = 0.f;
#pragma unroll
    for (int j = 0; j < 4; ++j){
      bf8 qv = qp[j];
      bf8 kv = *(const bf8*)(kb + j*8);
#pragma unroll
      for (int q = 0; q < 8; ++q){
        float d = bf2f((us)qv[q]) - bf2f((us)kv[q]);
        rel[j*8+q] = d; ss += d * d;
      }
    }
    ss += __shfl_xor(ss, 1, 64);
    ss += __shfl_xor(ss, 2, 64);
    float rinv = rsqrtf(ss + 1e-8f);
#pragma unroll
    for (int j = 0; j < 4; ++j){
      bf8 mv = *(const bf8*)(kb + 128 + j*8);
      bf8 bv = *(const bf8*)(kb + 256 + j*8);
      bf8 o;
#pragma unroll
      for (int q = 0; q < 8; ++q){
        float v = rel[j*8+q] * rinv * bf2f((us)mv[q]) + bf2f((us)bv[q]);
        o[q] = (short)f2bf(v);
      }
      int byte = r*256 + c4*64 + j*16; byte ^= (r & 7) << 4;
      *(bf8*)((char*)Ash + byte) = o;
    }
  }
  __syncthreads();   // (1)

  // GEMM1 from Ash
  f4 acc[2][4];
#pragma unroll
  for (int ct = 0; ct < 4; ++ct){ f4 t = {b1v[ct], b1v[ct], b1v[ct], b1v[ct]}; acc[0][ct] = t; acc[1][ct] = t; }
  bf8 a[2][4];
#pragma unroll
  for (int rt = 0; rt < 2; ++rt)
#pragma unroll
    for (int kk = 0; kk < 4; ++kk)
      a[rt][kk] = lds_frag(Ash, wr*32 + rt*16 + s, 256, kk*32 + g*8);
#pragma unroll
  for (int ct = 0; ct < 4; ++ct)
#pragma unroll
    for (int kk = 0; kk < 4; ++kk){
      acc[0][ct] = MFMA16(a[0][kk], B1[ct][kk], acc[0][ct]);
      acc[1][ct] = MFMA16(a[1][kk], B1[ct][kk], acc[1][ct]);
    }

  // LN + mish (internal sync (2) fences all Ash A-frag reads)
#pragma unroll
  for (int rt = 0; rt < 2; ++rt)
#pragma unroll
    for (int reg = 0; reg < 4; ++reg){
      float sm = acc[rt][0][reg] + acc[rt][1][reg] + acc[rt][2][reg] + acc[rt][3][reg];
      float sq = acc[rt][0][reg]*acc[rt][0][reg] + acc[rt][1][reg]*acc[rt][1][reg]
               + acc[rt][2][reg]*acc[rt][2][reg] + acc[rt][3][reg]*acc[rt][3][reg];
#pragma unroll
      for (int m = 1; m < 16; m <<= 1){ sm += __shfl_xor(sm, m, 64); sq += __shfl_xor(sq, m, 64); }
      if (s == 0){
        int row = wr*32 + rt*16 + g*4 + reg;
        rowsum[0][row][wc] = sm; rowsq[0][row][wc] = sq;
      }
    }
  __syncthreads();   // (2)
#pragma unroll
  for (int rt = 0; rt < 2; ++rt)
#pragma unroll
    for (int reg = 0; reg < 4; ++reg){
      int row = wr*32 + rt*16 + g*4 + reg;
      float sm = rowsum[0][row][0] + rowsum[0][row][1];
      float sq = rowsq[0][row][0] + rowsq[0][row][1];
      float mu = sm * (1.f/128.f);
      float var = sq * (1.f/128.f) - mu*mu;
      float rs = rsqrtf(var + 1e-5f);
#pragma unroll
      for (int ct = 0; ct < 4; ++ct)
        acc[rt][ct][reg] = mishf((acc[rt][ct][reg] - mu) * rs * gv[ct] + bev[ct]);
    }

  // T -> Ash (reuse; safe: all Ash reads happened before barrier (2))
  write_T(Ash, wr, wc, g, s, acc);
  __syncthreads();   // (3)

  // GEMM2 -> p = exp(w)
  f4 p[2][4];
#pragma unroll
  for (int ct = 0; ct < 4; ++ct){ f4 t = {b2v[ct], b2v[ct], b2v[ct], b2v[ct]}; p[0][ct] = t; p[1][ct] = t; }
  bf8 a2[2][4];
  load_a2(Ash, wr, g, s, a2);
#pragma unroll
  for (int ct = 0; ct < 4; ++ct)
#pragma unroll
    for (int kk = 0; kk < 4; ++kk){
      p[0][ct] = MFMA16(a2[0][kk], B2[ct][kk], p[0][ct]);
      p[1][ct] = MFMA16(a2[1][kk], B2[ct][kk], p[1][ct]);
    }
#pragma unroll
  for (int rt = 0; rt < 2; ++rt)
#pragma unroll
    for (int ct = 0; ct < 4; ++ct)
#pragma unroll
      for (int reg = 0; reg < 4; ++reg)
        p[rt][ct][reg] = __expf(p[rt][ct][reg]);

  __syncthreads();   // (4) a2 reads done; Ash reusable for p

  // p -> Ash (bf16, swizzled)
  write_T(Ash, wr, wc, g, s, p);
  __syncthreads();   // (5)

  { // block-level segment-sum by dst: ~6-7 distinct dst per 64 sorted edges.
    // Thread t owns column (t&127), rows [half*32, half*32+32). The dst-change
    // branch is wave-uniform (all lanes of a half share the row sequence).
    int col = tid & 127, half = tid >> 7;
    int rbeg = half * 32;
    float csum = 0.f;
    int prev = dsh[rbeg];
    float run = 0.f;
#pragma unroll 8
    for (int r = rbeg; r < rbeg + 32; ++r){
      int d = dsh[r];
      int byte = r*256 + col*2; byte ^= (r & 7) << 4;
      float v = bf2f(*(const us*)((const char*)Ash + byte));
      csum += v;
      if (d != prev){
        atomicAdd(&hacc[(size_t)prev * DN + col], run);
        run = v; prev = d;
      } else {
        run += v;
      }
    }
    atomicAdd(&hacc[(size_t)prev * DN + col], run);
    atomicAdd(&colsum8[(blockIdx.x & 7) * DN + col], csum);
  }
}

// ---------- final: h = mish(concat[node_feat, hacc/colsum] @ Wn1 + bn1) @ Wn2 + bn2 ----------
__global__ __launch_bounds__(256, 2)
void final_h(const float* __restrict__ nodef,
             const float* __restrict__ hacc,
             const float* __restrict__ colsum8,
             const us* __restrict__ Wn1T,
             const float* __restrict__ bn1,
             const us* __restrict__ Wn2T,
             const float* __restrict__ bn2,
             float* __restrict__ outh)
{
  __shared__ us Ash[64 * 256];   // [64 rows][256 cols] bf16, stride 512B
  __shared__ float rcs[DN];      // 1/colsum per column

  const int tid = threadIdx.x;
  const int r0 = blockIdx.x * 64;

  if (tid < DN){
    float ssum = 0.f;
#pragma unroll
    for (int x = 0; x < 8; ++x) ssum += colsum8[x * DN + tid];
    rcs[tid] = 1.f / ssum;
  }
  __syncthreads();

  { // stage node_feat -> cols 0..127, hacc/colsum -> cols 128..255
    int r = tid >> 2, c4 = tid & 3;
    int grow = r0 + r; if (grow >= NND) grow = NND - 1;
    const f4* np = (const f4*)(nodef + (size_t)grow * DN + c4 * 32);
    const f4* hp = (const f4*)(hacc + (size_t)grow * DN + c4 * 32);
#pragma unroll
    for (int j = 0; j < 4; ++j){
      f4 v0 = np[2*j], v1 = np[2*j+1];
      bf8 o;
#pragma unroll
      for (int q = 0; q < 4; ++q){ o[q] = (short)f2bf(v0[q]); o[4+q] = (short)f2bf(v1[q]); }
      int byte = r*512 + c4*64 + j*16; byte ^= (r & 7) << 4;
      *(bf8*)((char*)Ash + byte) = o;
      f4 h0 = hp[2*j], h1 = hp[2*j+1];
      bf8 o2;
#pragma unroll
      for (int q = 0; q < 4; ++q){
        o2[q]   = (short)f2bf(h0[q] * rcs[c4*32 + j*8 + q]);
        o2[4+q] = (short)f2bf(h1[q] * rcs[c4*32 + j*8 + 4 + q]);
      }
      int byte2 = r*512 + 256 + c4*64 + j*16; byte2 ^= (r & 7) << 4;
      *(bf8*)((char*)Ash + byte2) = o2;
    }
  }
  __syncthreads();

  const int lane = tid & 63, w = tid >> 6;
  const int wr = w >> 1, wc = w & 1;
  const int g = lane >> 4, s = lane & 15;

  float b1v[4], b2v[4];
#pragma unroll
  for (int ct = 0; ct < 4; ++ct){ int n = wc*64 + ct*16 + s; b1v[ct] = bn1[n]; b2v[ct] = bn2[n]; }

  f4 acc[2][4];
#pragma unroll
  for (int ct = 0; ct < 4; ++ct){ f4 t = {b1v[ct], b1v[ct], b1v[ct], b1v[ct]}; acc[0][ct] = t; acc[1][ct] = t; }

  bf8 a[2][8];
#pragma unroll
  for (int rt = 0; rt < 2; ++rt)
#pragma unroll
    for (int kk = 0; kk < 8; ++kk)
      a[rt][kk] = lds_frag(Ash, wr*32 + rt*16 + s, 512, kk*32 + g*8);
  __syncthreads();   // frag reads done -> Ash reusable as T

#pragma unroll
  for (int ct = 0; ct < 4; ++ct){
    int n = wc*64 + ct*16 + s;
#pragma unroll
    for (int kk = 0; kk < 8; ++kk){
      bf8 b = gfrag(Wn1T, n, 256, kk*32 + g*8);
      acc[0][ct] = MFMA16(a[0][kk], b, acc[0][ct]);
      acc[1][ct] = MFMA16(a[1][kk], b, acc[1][ct]);
    }
  }

#pragma unroll
  for (int rt = 0; rt < 2; ++rt)
#pragma unroll
    for (int ct = 0; ct < 4; ++ct)
#pragma unroll
      for (int reg = 0; reg < 4; ++reg)
        acc[rt][ct][reg] = mishf(acc[rt][ct][reg]);
  write_T((us*)Ash, wr, wc, g, s, acc);
  __syncthreads();

  f4 acc2[2][4];
#pragma unroll
  for (int ct = 0; ct < 4; ++ct){ f4 t = {b2v[ct], b2v[ct], b2v[ct], b2v[ct]}; acc2[0][ct] = t; acc2[1][ct] = t; }
  bf8 a2[2][4];
  load_a2((const us*)Ash, wr, g, s, a2);
#pragma unroll
  for (int ct = 0; ct < 4; ++ct){
    int n = wc*64 + ct*16 + s;
#pragma unroll
    for (int kk = 0; kk < 4; ++kk){
      bf8 b = gfrag(Wn2T, n, DN, kk*32 + g*8);
      acc2[0][ct] = MFMA16(a2[0][kk], b, acc2[0][ct]);
      acc2[1][ct] = MFMA16(a2[1][kk], b, acc2[1][ct]);
    }
  }
  store_tile<0>((void*)outh, NND, r0, wr, wc, g, s, DN, acc2);
}

struct WPrepArgs {
  const float* w[12];
  us* wt[12];
  int K[12];
};

// W^T bf16: wt[n*K + k] = bf16(W[k*128 + n])
__global__ void prep_weights(WPrepArgs a){
  int widx = blockIdx.y;
  int K = a.K[widx];
  int idx = blockIdx.x * 256 + threadIdx.x;
  if (idx >= DN * K) return;
  int kshift = (K == 256) ? 8 : 7;
  int n = idx >> kshift;
  int k = idx & (K - 1);
  a.wt[widx][idx] = f2bf(a.w[widx][(size_t)k * DN + n]);
}

extern "C" void kernel_launch(void* const* d_in, const int* in_sizes, int n_in,
                              void* d_out, int out_size, void* d_ws, size_t ws_size,
                              hipStream_t stream) {
  const float* node_feat = (const float*)d_in[0];
  const float* coordf    = (const float*)d_in[1];
  const float* Wq  = (const float*)d_in[2];
  const float* bq  = (const float*)d_in[3];
  const float* gq  = (const float*)d_in[4];
  const float* beq = (const float*)d_in[5];
  const float* Wk  = (const float*)d_in[6];
  const float* bk  = (const float*)d_in[7];
  const float* gk  = (const float*)d_in[8];
  const float* bek = (const float*)d_in[9];
  const float* Wm1 = (const float*)d_in[10];
  const float* bm1 = (const float*)d_in[11];
  const float* gm  = (const float*)d_in[12];
  const float* bem = (const float*)d_in[13];
  const float* Wm2 = (const float*)d_in[14];
  const float* bm2 = (const float*)d_in[15];
  const float* Wb1 = (const float*)d_in[16];
  const float* bb1 = (const float*)d_in[17];
  const float* gb  = (const float*)d_in[18];
  const float* beb = (const float*)d_in[19];
  const float* Wb2 = (const float*)d_in[20];
  const float* bb2 = (const float*)d_in[21];
  const float* Ww1 = (const float*)d_in[22];
  const float* bw1 = (const float*)d_in[23];
  const float* gw  = (const float*)d_in[24];
  const float* bew = (const float*)d_in[25];
  const float* Ww2 = (const float*)d_in[26];
  const float* bw2 = (const float*)d_in[27];
  const float* Wn1 = (const float*)d_in[28];
  const float* bn1 = (const float*)d_in[29];
  const float* Wn2 = (const float*)d_in[30];
  const float* bn2 = (const float*)d_in[31];
  const float* Wc1 = (const float*)d_in[32];
  const float* bc1 = (const float*)d_in[33];
  const float* Wc2 = (const float*)d_in[34];
  const int* srcI  = (const int*)d_in[35];
  const int* dstI  = (const int*)d_in[36];

  char* ws = (char*)d_ws;
  size_t off = 0;
  auto alloc = [&](size_t bytes) -> char* {
    char* p = ws + off;
    off += (bytes + 255) & ~(size_t)255;
    return p;
  };
  us*    qt      = (us*)alloc((size_t)NND * DN * 2);
  us*    kmb     = (us*)alloc((size_t)NND * 384 * 2);
  float* hacc    = (float*)alloc((size_t)NND * DN * 4);
  float* colsum8 = (float*)alloc(8 * DN * 4);
  int*   deg     = (int*)alloc((size_t)NND * 4);
  int*   fillctr = (int*)alloc((size_t)NND * 4);
  int*   ssorted = (int*)alloc((size_t)NED * 4);
  int*   dsorted = (int*)alloc((size_t)NED * 4);
  int*   bsum    = (int*)alloc((size_t)NSCAN * 4);
  int*   boff    = (int*)alloc((size_t)NSCAN * 4);
  us*    wtb     = (us*)alloc((size_t)12 * 16384 * 2);

  // zero the atomic accumulators (hacc + colsum8 are adjacent)
  hipMemsetAsync(hacc, 0, (size_t)NND * DN * 4 + 8 * DN * 4, stream);
  hipMemsetAsync(deg, 0, (size_t)NND * 4, stream);

  WPrepArgs pa;
  const float* wsrc[12] = {Wq, Wk, Wm1, Wm2, Wb1, Wb2, Ww1, Ww2, Wc1, Wc2, Wn2, Wn1};
  for (int i = 0; i < 12; ++i){
    pa.w[i] = wsrc[i];
    pa.wt[i] = wtb + (size_t)i * 16384;
    pa.K[i] = (i == 11) ? 256 : 128;
  }
  prep_weights<<<dim3(128, 12), 256, 0, stream>>>(pa);

  // CSR positions + edge sort by dst
  csr_count<<<(NED + 255) / 256, 256, 0, stream>>>(dstI, deg);
  csr_blocksum<<<NSCAN, 1024, 0, stream>>>(deg, bsum);
  csr_scanroot<<<1, 64, 0, stream>>>(bsum, boff);
  csr_scatter<<<NSCAN, 1024, 0, stream>>>(deg, boff, fillctr);
  csr_fill<<<(NED + 255) / 256, 256, 0, stream>>>(srcI, dstI, fillctr, ssorted, dsorted);

  const int NB = (NND + 63) / 64;  // 782

  node_fused<<<NB, 256, 0, stream>>>(coordf,
      pa.wt[0], bq, gq, beq,
      pa.wt[1], bk, gk, bek,
      pa.wt[2], bm1, gm, bem, pa.wt[3], bm2,
      pa.wt[4], bb1, gb, beb, pa.wt[5], bb2,
      pa.wt[8], bc1, pa.wt[9],
      qt, kmb, (float*)d_out + (size_t)NND * DN);

  edge_kernel<<<NED / 64, 256, 0, stream>>>(qt, kmb, pa.wt[6], pa.wt[7],
                                            bw1, gw, bew, bw2, ssorted, dsorted,
                                            hacc, colsum8);

  final_h<<<NB, 256, 0, stream>>>(node_feat, hacc, colsum8,
                                  pa.wt[11], bn1, pa.wt[10], bn2, (float*)d_out);
}